// Round 11
// baseline (1438.656 us; speedup 1.0000x reference)
//
#include <hip/hip_runtime.h>
#include <hip/hip_bf16.h>

#define T_SEQ 2048
#define DMODEL 512
#define CEXP 512

typedef short s16x4 __attribute__((ext_vector_type(4)));
typedef short s16x8 __attribute__((ext_vector_type(8)));
typedef float f32x4 __attribute__((ext_vector_type(4)));

__device__ __forceinline__ float geluf(float x){
  float x3 = x*x*x;
  return 0.5f*x*(1.f + tanhf(0.7978845608028654f*(x + 0.044715f*x3)));
}

// fp32 -> bf16 (RNE), bit-level
__device__ __forceinline__ unsigned short f2b(float x){
  unsigned int u = __float_as_uint(x);
  u += 0x7fffu + ((u >> 16) & 1u);
  return (unsigned short)(u >> 16);
}

// GEMM params (by value to kernels; strides in elements)
struct GP {
  const float* A; long As;
  const float* W; long Ws;
  const float* R; long Rs;
  float* O; long Os;
  int M, N, K, act;
};

// ---------------- embed (float4) ----------------
__global__ void embed_kernel(const int* __restrict__ ids, const float* __restrict__ ew,
                             float* __restrict__ h){
  int idx = blockIdx.x*256 + threadIdx.x;   // T*128 exact
  int t = idx >> 7, d4 = idx & 127;
  *(float4*)&h[(size_t)idx*4] = *(const float4*)&ew[(size_t)ids[t]*DMODEL + d4*4];
}

// ---------------- rope table ----------------
__global__ void rope_table_kernel(float* __restrict__ cosb, float* __restrict__ sinb){
  int idx = blockIdx.x*256 + threadIdx.x;   // T*64 exact
  int t = idx >> 6, i = idx & 63, j = i & 31;
  float inv = powf(10000.f, -(float)(2*j)/64.f);
  float a = (float)t * inv;
  cosb[idx] = cosf(a);
  sinb[idx] = sinf(a);
}

// ---------------- rmsnorm (grouped rows; per-group scale) ----------------
__global__ void rmsnorm_kernel(const float* __restrict__ in, float* __restrict__ out,
                               const float* __restrict__ scale,
                               int rows_per_group, long gstride, int scale_stride){
  int row = blockIdx.x;
  int g = row / rows_per_group, lr = row - g*rows_per_group;
  const float* x = in  + (size_t)g*gstride + (size_t)lr*DMODEL;
  float*       y = out + (size_t)g*gstride + (size_t)lr*DMODEL;
  const float* s = scale + (size_t)g*scale_stride;
  int tid = threadIdx.x;
  float ss = 0.f;
  for (int i = tid; i < DMODEL; i += 256){ float v = x[i]; ss += v*v; }
  __shared__ float red[256];
  red[tid] = ss; __syncthreads();
  for (int st = 128; st > 0; st >>= 1){ if (tid < st) red[tid] += red[tid+st]; __syncthreads(); }
  float r = rsqrtf(red[0]*(1.f/DMODEL) + 1e-6f);
  for (int i = tid; i < DMODEL; i += 256) y[i] = x[i]*r*s[i];
}

// r11: both hop rmsnorm halves in one launch (block picks half). Per-row math
// identical to rmsnorm_kernel -> bit-identical.
__global__ void rmsnorm_dual_kernel(const float* __restrict__ in1, float* __restrict__ out1,
                                    const float* __restrict__ sc1,
                                    const float* __restrict__ in2, float* __restrict__ out2,
                                    const float* __restrict__ sc2,
                                    int rows_per_group, long gstride, int scale_stride, int nrows){
  int row = blockIdx.x;
  const float* in; float* out; const float* scale;
  if (row < nrows){ in = in1; out = out1; scale = sc1; }
  else            { in = in2; out = out2; scale = sc2; row -= nrows; }
  int g = row / rows_per_group, lr = row - g*rows_per_group;
  const float* x = in  + (size_t)g*gstride + (size_t)lr*DMODEL;
  float*       y = out + (size_t)g*gstride + (size_t)lr*DMODEL;
  const float* s = scale + (size_t)g*scale_stride;
  int tid = threadIdx.x;
  float ss = 0.f;
  for (int i = tid; i < DMODEL; i += 256){ float v = x[i]; ss += v*v; }
  __shared__ float red[256];
  red[tid] = ss; __syncthreads();
  for (int st = 128; st > 0; st >>= 1){ if (tid < st) red[tid] += red[tid+st]; __syncthreads(); }
  float r = rsqrtf(red[0]*(1.f/DMODEL) + 1e-6f);
  for (int i = tid; i < DMODEL; i += 256) y[i] = x[i]*r*s[i];
}

__global__ void final_rmsnorm_kernel(const float* __restrict__ in, float* __restrict__ out,
                                     const float* __restrict__ scale){
  int row = blockIdx.x;
  const float* x = in + (size_t)row*DMODEL;
  int tid = threadIdx.x;
  float ss = 0.f;
  for (int i = tid; i < DMODEL; i += 256){ float v = x[i]; ss += v*v; }
  __shared__ float red[256];
  red[tid] = ss; __syncthreads();
  for (int st = 128; st > 0; st >>= 1){ if (tid < st) red[tid] += red[tid+st]; __syncthreads(); }
  float r = rsqrtf(red[0]*(1.f/DMODEL) + 1e-6f);
  for (int i = tid; i < DMODEL; i += 256)
    out[(size_t)row*DMODEL + i] = x[i]*r*scale[i];
}

// ---------------- fp32 GEMM 64x64 body (register-prefetch, bit-identical order) ----------------
__device__ __forceinline__ void gemm64_body(GP g, int bx, int by, int bz){
  const float* A = g.A + (size_t)bz*g.As;
  const float* W = g.W + (size_t)bz*g.Ws;
  const float* Res = g.R ? g.R + (size_t)bz*g.Rs : nullptr;
  float* Out = g.O + (size_t)bz*g.Os;
  int M = g.M, N = g.N, K = g.K, act = g.act;
  __shared__ float As[16][68];
  __shared__ float Ws[16][68];
  int tid = threadIdx.x;
  int tx = tid & 15, ty = tid >> 4;
  int row0 = bx*64, col0 = by*64;
  float acc[4][4] = {{0.f}};
  int sm = tid >> 2;               // staged row 0..63
  int skq = (tid & 3) << 2;        // staged k-chunk 0,4,8,12
  int gm = row0 + sm, gn = col0 + sm;

  float4 va = make_float4(0.f,0.f,0.f,0.f);
  float4 vw = make_float4(0.f,0.f,0.f,0.f);
  if (gm < M) va = *(const float4*)&A[(size_t)gm*K + skq];
  if (gn < N) vw = *(const float4*)&W[(size_t)gn*K + skq];

  for (int k0 = 0; k0 < K; k0 += 16){
    __syncthreads();
    As[skq+0][sm] = va.x; As[skq+1][sm] = va.y; As[skq+2][sm] = va.z; As[skq+3][sm] = va.w;
    Ws[skq+0][sm] = vw.x; Ws[skq+1][sm] = vw.y; Ws[skq+2][sm] = vw.z; Ws[skq+3][sm] = vw.w;
    __syncthreads();
    if (k0 + 16 < K){
      if (gm < M) va = *(const float4*)&A[(size_t)gm*K + k0 + 16 + skq];
      if (gn < N) vw = *(const float4*)&W[(size_t)gn*K + k0 + 16 + skq];
    }
    #pragma unroll
    for (int kk = 0; kk < 16; ++kk){
      float4 av = *(const float4*)&As[kk][ty*4];
      float4 wv = *(const float4*)&Ws[kk][tx*4];
      float a[4] = {av.x, av.y, av.z, av.w};
      float w[4] = {wv.x, wv.y, wv.z, wv.w};
      #pragma unroll
      for (int i = 0; i < 4; ++i)
        #pragma unroll
        for (int j = 0; j < 4; ++j)
          acc[i][j] += a[i]*w[j];
    }
  }
  #pragma unroll
  for (int i = 0; i < 4; ++i){
    int om = row0 + ty*4 + i;
    if (om >= M) continue;
    #pragma unroll
    for (int j = 0; j < 4; ++j){
      int on = col0 + tx*4 + j;
      if (on >= N) continue;
      float v = acc[i][j];
      if (act == 1) v = geluf(v);
      if (Res) v += Res[(size_t)om*N + on];
      Out[(size_t)om*N + on] = v;
    }
  }
}

__global__ __launch_bounds__(256)
void gemm_kernel(GP g){ gemm64_body(g, blockIdx.x, blockIdx.y, blockIdx.z); }

// dual: y < ysplit -> g1, else g2 (y shifted). Each block computes exactly
// what it did as a standalone launch -> bit-identical.
__global__ __launch_bounds__(256)
void gemm_dual(GP g1, GP g2, int ysplit){
  bool first = (int)blockIdx.y < ysplit;
  GP g = first ? g1 : g2;
  int by = first ? blockIdx.y : blockIdx.y - ysplit;
  gemm64_body(g, blockIdx.x, by, blockIdx.z);
}

// ---------------- fp32 GEMM 128x128, 8x8/thread (N=1536/2048 shapes) ----------------
__global__ __launch_bounds__(256)
void gemm128(const float* __restrict__ A, long Astride,
             const float* __restrict__ W, long Wstride,
             const float* __restrict__ Res, long Rstride,
             float* __restrict__ Out, long Ostride,
             int M, int N, int K, int act){
  int b = blockIdx.z;
  A += (size_t)b*Astride; W += (size_t)b*Wstride; Out += (size_t)b*Ostride;
  if (Res) Res += (size_t)b*Rstride;
  __shared__ float As[16][132];
  __shared__ float Ws[16][132];
  int tid = threadIdx.x;
  int r0 = (tid >> 4) * 8;
  int c0 = (tid & 15) * 8;
  int row0 = blockIdx.x*128, col0 = blockIdx.y*128;
  int sr = tid >> 1;
  int sc = (tid & 1) * 8;
  float acc[8][8] = {{0.f}};

  float4 a0 = *(const float4*)&A[(size_t)(row0+sr)*K + sc];
  float4 a1 = *(const float4*)&A[(size_t)(row0+sr)*K + sc + 4];
  float4 w0 = *(const float4*)&W[(size_t)(col0+sr)*K + sc];
  float4 w1 = *(const float4*)&W[(size_t)(col0+sr)*K + sc + 4];

  for (int k0 = 0; k0 < K; k0 += 16){
    __syncthreads();
    As[sc+0][sr]=a0.x; As[sc+1][sr]=a0.y; As[sc+2][sr]=a0.z; As[sc+3][sr]=a0.w;
    As[sc+4][sr]=a1.x; As[sc+5][sr]=a1.y; As[sc+6][sr]=a1.z; As[sc+7][sr]=a1.w;
    Ws[sc+0][sr]=w0.x; Ws[sc+1][sr]=w0.y; Ws[sc+2][sr]=w0.z; Ws[sc+3][sr]=w0.w;
    Ws[sc+4][sr]=w1.x; Ws[sc+5][sr]=w1.y; Ws[sc+6][sr]=w1.z; Ws[sc+7][sr]=w1.w;
    __syncthreads();
    if (k0 + 16 < K){
      a0 = *(const float4*)&A[(size_t)(row0+sr)*K + k0 + 16 + sc];
      a1 = *(const float4*)&A[(size_t)(row0+sr)*K + k0 + 16 + sc + 4];
      w0 = *(const float4*)&W[(size_t)(col0+sr)*K + k0 + 16 + sc];
      w1 = *(const float4*)&W[(size_t)(col0+sr)*K + k0 + 16 + sc + 4];
    }
    #pragma unroll
    for (int kk = 0; kk < 16; ++kk){
      float a[8], w[8];
      *(float4*)&a[0] = *(const float4*)&As[kk][r0];
      *(float4*)&a[4] = *(const float4*)&As[kk][r0+4];
      *(float4*)&w[0] = *(const float4*)&Ws[kk][c0];
      *(float4*)&w[4] = *(const float4*)&Ws[kk][c0+4];
      #pragma unroll
      for (int i = 0; i < 8; ++i)
        #pragma unroll
        for (int j = 0; j < 8; ++j)
          acc[i][j] += a[i]*w[j];
    }
  }

  #pragma unroll
  for (int i = 0; i < 8; ++i){
    int gm = row0 + r0 + i;
    #pragma unroll
    for (int jj = 0; jj < 2; ++jj){
      int gn = col0 + c0 + jj*4;
      float4 v;
      v.x = acc[i][jj*4+0]; v.y = acc[i][jj*4+1];
      v.z = acc[i][jj*4+2]; v.w = acc[i][jj*4+3];
      if (act == 1){ v.x = geluf(v.x); v.y = geluf(v.y); v.z = geluf(v.z); v.w = geluf(v.w); }
      if (Res){
        float4 rv = *(const float4*)&Res[(size_t)gm*N + gn];
        v.x += rv.x; v.y += rv.y; v.z += rv.z; v.w += rv.w;
      }
      *(float4*)&Out[(size_t)gm*N + gn] = v;
    }
  }
}

// ---------------- MFMA bf16 GEMM body (non-routing: last-hop experts) ----------------
__device__ __forceinline__ void mfma_body(GP g, int bx, int by, int bz){
  const float* A = g.A + (size_t)bz*g.As;
  const float* W = g.W + (size_t)bz*g.Ws;
  const float* Res = g.R ? g.R + (size_t)bz*g.Rs : nullptr;
  float* Out = g.O + (size_t)bz*g.Os;
  int N = g.N, K = g.K, act = g.act;

  __shared__ short As[128][40];   // 80 B row stride: 16B-aligned, <=2-way banks
  __shared__ short Ws[128][40];

  int tid = threadIdx.x;
  int l = tid & 63, w = tid >> 6;
  int wrow = (w >> 1)*64, wcol = (w & 1)*64;
  int row0 = bx*128, col0 = by*128;
  int lm = l & 15, lq = l >> 4;

  f32x4 acc[4][4];
  #pragma unroll
  for (int i = 0; i < 4; ++i)
    #pragma unroll
    for (int j = 0; j < 4; ++j)
      acc[i][j] = (f32x4){0.f,0.f,0.f,0.f};

  for (int k0 = 0; k0 < K; k0 += 32){
    #pragma unroll
    for (int t = 0; t < 4; ++t){
      int f4 = tid + t*256;
      int r = f4 >> 3, kq = f4 & 7;
      float4 va = *(const float4*)&A[(size_t)(row0 + r)*K + k0 + kq*4];
      s16x4 pa; pa[0]=(short)f2b(va.x); pa[1]=(short)f2b(va.y); pa[2]=(short)f2b(va.z); pa[3]=(short)f2b(va.w);
      *(s16x4*)&As[r][kq*4] = pa;
      float4 vw = *(const float4*)&W[(size_t)(col0 + r)*K + k0 + kq*4];
      s16x4 pw; pw[0]=(short)f2b(vw.x); pw[1]=(short)f2b(vw.y); pw[2]=(short)f2b(vw.z); pw[3]=(short)f2b(vw.w);
      *(s16x4*)&Ws[r][kq*4] = pw;
    }
    __syncthreads();

    s16x8 af[4], bf[4];
    #pragma unroll
    for (int rt = 0; rt < 4; ++rt)
      af[rt] = *(s16x8*)&As[wrow + rt*16 + lm][lq*8];
    #pragma unroll
    for (int ct = 0; ct < 4; ++ct)
      bf[ct] = *(s16x8*)&Ws[wcol + ct*16 + lm][lq*8];
    #pragma unroll
    for (int rt = 0; rt < 4; ++rt)
      #pragma unroll
      for (int ct = 0; ct < 4; ++ct)
        acc[rt][ct] = __builtin_amdgcn_mfma_f32_16x16x32_bf16(af[rt], bf[ct], acc[rt][ct], 0, 0, 0);
    __syncthreads();
  }

  #pragma unroll
  for (int rt = 0; rt < 4; ++rt){
    #pragma unroll
    for (int p = 0; p < 4; ++p){
      int row = row0 + wrow + rt*16 + lq*4 + p;
      #pragma unroll
      for (int ct = 0; ct < 4; ++ct){
        int col = col0 + wcol + ct*16 + lm;
        float v = acc[rt][ct][p];
        if (act == 1) v = geluf(v);
        if (Res) v += Res[(size_t)row*N + col];
        Out[(size_t)row*N + col] = v;
      }
    }
  }
}

__global__ __launch_bounds__(256)
void gemm_mfma(GP g){ mfma_body(g, blockIdx.x, blockIdx.y, blockIdx.z); }

__global__ __launch_bounds__(256)
void mfma_dual(GP g1, GP g2, int ysplit){
  bool first = (int)blockIdx.y < ysplit;
  GP g = first ? g1 : g2;
  int by = first ? blockIdx.y : blockIdx.y - ysplit;
  mfma_body(g, blockIdx.x, by, blockIdx.z);
}

// ---------------- RoPE apply in-place on qkv rows ----------------
__global__ void rope_kernel(float* __restrict__ qkv, const float* __restrict__ cosb,
                            const float* __restrict__ sinb, const int* __restrict__ map,
                            int map_gstride, int rows_per_group){
  int idx = blockIdx.x*256 + threadIdx.x;   // rows*512 exact
  int row = idx >> 9;
  int rem = idx & 511;
  int sec = rem >> 8;           // 0=q, 1=k
  int hh  = (rem >> 5) & 7;
  int j   = rem & 31;
  int t;
  if (map){
    t = map[(row/rows_per_group)*map_gstride + (row % rows_per_group)];
    if (t < 0) return;
  } else {
    t = row;
  }
  float c = cosb[t*64 + j], s = sinb[t*64 + j];
  float* p = qkv + (size_t)row*1536 + sec*512 + hh*64;
  float a = p[j], b = p[j+32];
  p[j]    = a*c - b*s;
  p[j+32] = b*c + a*s;
}

// ---------------- flash attention: paired 16q tiles, XCD-swizzled, 2-tile K stage ----------------
// r11: stage TWO 64-row K-tiles per barrier pair (Ks[128][68], 43.5KB -> still
// 3 blocks/CU by LDS). Halves the per-block barrier count (34->17) and doubles
// the stage burst (better memory-level parallelism). Compute iterates the two
// sub-tiles in ascending kt (uniform break) -> same loads, same FMA/shuffle
// order as r10 -> bit-identical, routing-safe. No conditional register arrays
// spanning barriers (r9 scratch-spill lesson). XCD swizzle (r8) + heavy+light
// pairing (r7) retained.
__global__ __launch_bounds__(256, 3)
void fattn_kernel(const float* __restrict__ qkv, float* __restrict__ ctx, int C){
  int tps = C >> 4;                 // 16-row q tiles per sequence (even)
  int pairs = tps >> 1;
  int lin = blockIdx.y * gridDim.x + blockIdx.x;   // hardware linear id
  int hh  = lin & 7;                // XCD-local head
  int bx  = lin >> 3;
  int seq = bx / pairs;
  int pr  = bx - seq*pairs;
  size_t base = (size_t)seq * C * 1536;
  const float* Qg = qkv + base + hh*64;
  const float* Kg = qkv + base + 512 + hh*64;
  const float* Vg = qkv + base + 1024 + hh*64;

  __shared__ float Qs[16][68];
  __shared__ float Ks[128][68];
  __shared__ float Ps[16][68];

  int tid = threadIdx.x;
  int tx = tid & 15, ty = tid >> 4;   // ty = owned q row (0..15)

  #pragma unroll 1
  for (int half = 0; half < 2; ++half){
    int lt = half ? pr : (tps - 1 - pr);   // heavy tile first
    int q0 = lt << 4;
    if (half) __syncthreads();             // all half-0 LDS reads complete

    // Q stage: exactly one float4 per thread (row ty: same-wave use only)
    *(float4*)&Qs[ty][tx*4] = *(const float4*)&Qg[(size_t)(q0 + ty)*1536 + tx*4];

    float o[4] = {0.f, 0.f, 0.f, 0.f};
    float mrow = -1e30f, lrow = 0.f;

    int nkt = (lt >> 2) + 1;            // k-tiles are 64 wide
    int nks = (nkt + 1) >> 1;           // stage steps (2 tiles each)
    #pragma unroll 1
    for (int ks = 0; ks < nks; ++ks){
      int kbase = ks << 7;              // 128 rows per stage
      int rows = (nkt << 6) - kbase; if (rows > 128) rows = 128;
      if (ks) __syncthreads();          // previous stage's Ks reads complete
      for (int i = tid; i < rows*16; i += 256){
        int r = i >> 4, dq = i & 15;
        *(float4*)&Ks[r][dq*4] = *(const float4*)&Kg[(size_t)(kbase + r)*1536 + dq*4];
      }
      __syncthreads();

      #pragma unroll 1
      for (int sub = 0; sub < 2; ++sub){
        int kt = (ks << 1) + sub;
        if (kt >= nkt) break;           // block-uniform
        int k0 = kt << 6;
        int kro = sub << 6;             // row offset within Ks

        // issue first V row-group early: latency hides under QK^T
        const float* vbase = Vg + (size_t)k0*1536 + tx*4;
        float4 nv0 = *(const float4*)(vbase + 0*1536);
        float4 nv1 = *(const float4*)(vbase + 1*1536);
        float4 nv2 = *(const float4*)(vbase + 2*1536);
        float4 nv3 = *(const float4*)(vbase + 3*1536);

        float s[4] = {0.f, 0.f, 0.f, 0.f};
        #pragma unroll
        for (int d = 0; d < 64; d += 4){
          float4 qv = *(const float4*)&Qs[ty][d];
          float4 kv[4];
          #pragma unroll
          for (int j = 0; j < 4; ++j) kv[j] = *(const float4*)&Ks[kro + j*16+tx][d];
          #pragma unroll
          for (int j = 0; j < 4; ++j)
            s[j] += qv.x*kv[j].x + qv.y*kv[j].y + qv.z*kv[j].z + qv.w*kv[j].w;
        }
        {
          int q = q0 + ty;
          #pragma unroll
          for (int j = 0; j < 4; ++j){
            int k = k0 + j*16 + tx;
            s[j] = (k <= q) ? s[j]*0.125f : -1e30f;
          }
        }
        {
          float m2 = fmaxf(fmaxf(s[0], s[1]), fmaxf(s[2], s[3]));
          #pragma unroll
          for (int off = 1; off < 16; off <<= 1)
            m2 = fmaxf(m2, __shfl_xor(m2, off, 64));
          float mnew = fmaxf(mrow, m2);
          float alpha = __expf(mrow - mnew);
          float p0 = __expf(s[0] - mnew);
          float p1 = __expf(s[1] - mnew);
          float p2 = __expf(s[2] - mnew);
          float p3 = __expf(s[3] - mnew);
          float rs = (p0 + p1) + (p2 + p3);
          #pragma unroll
          for (int off = 1; off < 16; off <<= 1)
            rs += __shfl_xor(rs, off, 64);
          lrow = lrow*alpha + rs;
          mrow = mnew;
          #pragma unroll
          for (int j = 0; j < 4; ++j) o[j] *= alpha;
          Ps[ty][tx]    = p0;
          Ps[ty][16+tx] = p1;
          Ps[ty][32+tx] = p2;
          Ps[ty][48+tx] = p3;
        }
        {
          #pragma unroll
          for (int kc = 0; kc < 16; ++kc){
            float4 v0 = nv0, v1 = nv1, v2 = nv2, v3 = nv3;
            if (kc < 15){
              const float* nb = vbase + (size_t)(kc+1)*4*1536;
              nv0 = *(const float4*)(nb + 0*1536);
              nv1 = *(const float4*)(nb + 1*1536);
              nv2 = *(const float4*)(nb + 2*1536);
              nv3 = *(const float4*)(nb + 3*1536);
            }
            float4 pr4 = *(const float4*)&Ps[ty][kc*4];
            o[0] += pr4.x*v0.x + pr4.y*v1.x + pr4.z*v2.x + pr4.w*v3.x;
            o[1] += pr4.x*v0.y + pr4.y*v1.y + pr4.z*v2.y + pr4.w*v3.y;
            o[2] += pr4.x*v0.z + pr4.y*v1.z + pr4.z*v2.z + pr4.w*v3.z;
            o[3] += pr4.x*v0.w + pr4.y*v1.w + pr4.z*v2.w + pr4.w*v3.w;
          }
        }
      }
    }

    float inv = 1.f / lrow;
    float4 res;
    res.x = o[0]*inv; res.y = o[1]*inv; res.z = o[2]*inv; res.w = o[3]*inv;
    *(float4*)(ctx + (size_t)(seq*C + q0 + ty)*512 + hh*64 + tx*4) = res;
  }
}

// ---------------- router: softmax over 9, top-2 mask ----------------
__global__ void router_kernel(const float* __restrict__ logits, float* __restrict__ probs,
                              int* __restrict__ maskb){
  int t = blockIdx.x*256 + threadIdx.x;
  if (t >= T_SEQ) return;
  float v[9];
  float mx = -1e30f;
  for (int e = 0; e < 9; ++e){ v[e] = logits[t*9+e]; mx = fmaxf(mx, v[e]); }
  float s = 0.f;
  for (int e = 0; e < 9; ++e) s += expf(v[e]-mx);
  float inv = 1.f/s;
  for (int e = 0; e < 8; ++e) probs[t*8+e] = expf(v[e]-mx)*inv;
  int i1 = 0;
  for (int e = 1; e < 9; ++e) if (v[e] > v[i1]) i1 = e;
  int i2 = -1;
  for (int e = 0; e < 9; ++e){ if (e == i1) continue; if (i2 < 0 || v[e] > v[i2]) i2 = e; }
  maskb[t] = (1<<i1) | (1<<i2);
}

__global__ void seti_kernel(int* __restrict__ p, int v, int n){
  int i = blockIdx.x*256 + threadIdx.x;
  if (i < n) p[i] = v;
}

// ---------------- capacity ranking ----------------
__global__ void rank_kernel(const float* __restrict__ probs, const int* __restrict__ maskb,
                            int* __restrict__ t2s, int* __restrict__ s2t, float* __restrict__ cw){
  int idx = blockIdx.x*256 + threadIdx.x;   // 8*T exact
  int e = idx / T_SEQ, t = idx - e*T_SEQ;
  __shared__ float spm[T_SEQ];
  int tid = threadIdx.x;
  for (int i = tid; i < T_SEQ; i += 256)
    spm[i] = ((maskb[i]>>e)&1) ? probs[i*8+e] : -1.0f;
  __syncthreads();
  int slot = -1; float w = 0.f;
  if ((maskb[t]>>e)&1){
    float p = probs[t*8+e];
    int rank = 0;
    #pragma unroll 8
    for (int t2 = 0; t2 < T_SEQ; ++t2){
      float p2 = spm[t2];
      rank += (p2 > p || (p2 == p && t2 < t)) ? 1 : 0;
    }
    if (rank < CEXP){ slot = rank; w = p; s2t[e*CEXP + rank] = t; }
  }
  t2s[t*8+e] = slot;
  cw[t*8+e] = w;
}

// ---------------- gather (float4) ----------------
__global__ void gather_kernel(const float* __restrict__ h, const int* __restrict__ s2t,
                              float* __restrict__ xin){
  int idx = blockIdx.x*256 + threadIdx.x;   // 8*CEXP*128 exact
  int row = idx >> 7, d4 = idx & 127;
  int t = s2t[row];
  float4 v = make_float4(0.f,0.f,0.f,0.f);
  if (t >= 0) v = *(const float4*)&h[(size_t)t*DMODEL + d4*4];
  *(float4*)&xin[(size_t)idx*4] = v;
}

// ---------------- combine (float4; per-element order unchanged) ----------------
__global__ void combine_kernel(float* __restrict__ h, const float* __restrict__ eout,
                               const int* __restrict__ t2s, const float* __restrict__ cw){
  int idx = blockIdx.x*256 + threadIdx.x;   // T*128 exact
  int t = idx >> 7, d4 = idx & 127;
  float4 acc = make_float4(0.f,0.f,0.f,0.f);
  float rho = 0.f;
  for (int e = 0; e < 8; ++e){
    int c = t2s[t*8+e];
    if (c >= 0){
      float w = cw[t*8+e];
      rho += w;
      float4 ev = *(const float4*)&eout[((size_t)e*CEXP + c)*DMODEL + d4*4];
      acc.x += w*ev.x; acc.y += w*ev.y; acc.z += w*ev.z; acc.w += w*ev.w;
    }
  }
  float4 hv = *(float4*)&h[(size_t)idx*4];
  float4 r;
  r.x = hv.x + acc.x - rho*hv.x;
  r.y = hv.y + acc.y - rho*hv.y;
  r.z = hv.z + acc.z - rho*hv.z;
  r.w = hv.w + acc.w - rho*hv.w;
  *(float4*)&h[(size_t)idx*4] = r;
}

extern "C" void kernel_launch(void* const* d_in, const int* in_sizes, int n_in,
                              void* d_out, int out_size, void* d_ws, size_t ws_size,
                              hipStream_t stream){
  const int*   ids      = (const int*)  d_in[0];
  const float* embed_w  = (const float*)d_in[1];
  const float* router_w = (const float*)d_in[2];
  const float* attn_qkv = (const float*)d_in[3];
  const float* attn_o   = (const float*)d_in[4];
  const float* attn_ln  = (const float*)d_in[5];
  const float* ffn_w1   = (const float*)d_in[6];
  const float* ffn_w2   = (const float*)d_in[7];
  const float* ffn_ln   = (const float*)d_in[8];
  const float* bb_qkv   = (const float*)d_in[9];
  const float* bb_o     = (const float*)d_in[10];
  const float* bb_ln    = (const float*)d_in[11];
  const float* lnout_s  = (const float*)d_in[12];
  float* out = (float*)d_out;

  // ---- workspace layout (floats) ----
  float* W    = (float*)d_ws;
  float* h    = W;                 // 2048*512
  float* cosb = h    + 1048576;    // 2048*64
  float* sinb = cosb + 131072;
  float* xin  = sinb + 131072;     // 8*512*512
  float* u    = xin  + 2097152;
  float* big  = u    + 2097152;    // max(2048*1536, 4*512*2048)
  float* ctx  = big  + 4194304;    // 2048*512
  float* eout = ctx  + 1048576;
  float* logits = eout + 2097152;
  float* probs  = logits + 18432;
  float* cw     = probs  + 16384;
  int* ibase = (int*)(cw + 16384);
  int* maskb = ibase;
  int* t2s   = maskb + 2048;
  int* s2t   = t2s   + 16384;

  embed_kernel<<<1024, 256, 0, stream>>>(ids, embed_w, h);
  rope_table_kernel<<<512, 256, 0, stream>>>(cosb, sinb);

  // ---- backbone attention block (fp32: feeds routing) ----
  rmsnorm_kernel<<<2048, 256, 0, stream>>>(h, u, bb_ln, 2048, 0, 0);
  gemm128<<<dim3(16,12,1), 256, 0, stream>>>(u, 0, bb_qkv, 0, nullptr, 0, big, 0,
                                             2048, 1536, 512, 0);
  rope_kernel<<<4096, 256, 0, stream>>>(big, cosb, sinb, nullptr, 0, 2048);
  fattn_kernel<<<dim3(64,8,1), 256, 0, stream>>>(big, ctx, 2048);
  gemm_kernel<<<dim3(32,8,1), 256, 0, stream>>>(
      GP{ctx, 0, bb_o, 0, h, 0, h, 0, 2048, 512, 512, 0});

  // ---- hops ----
  for (int hop = 0; hop < 2; ++hop){
    const float* wr = router_w + (size_t)hop*9*512;
    gemm_kernel<<<dim3(32,1,1), 256, 0, stream>>>(
        GP{h, 0, wr, 0, nullptr, 0, logits, 0, 2048, 9, 512, 0});
    router_kernel<<<8, 256, 0, stream>>>(logits, probs, maskb);
    seti_kernel<<<16, 256, 0, stream>>>(s2t, -1, 4096);
    rank_kernel<<<64, 256, 0, stream>>>(probs, maskb, t2s, s2t, cw);
    gather_kernel<<<2048, 256, 0, stream>>>(h, s2t, xin);

    rmsnorm_dual_kernel<<<4096, 256, 0, stream>>>(xin,          u,          attn_ln,
                                                  xin + 262144, u + 262144, ffn_ln,
                                                  512, 524288, 512, 2048);

    if (hop == 0){
      // hop 1 feeds hop-2 routing: keep fp32 numerics (round-4 verified).
      gemm128<<<dim3(4,12,4), 256, 0, stream>>>(u, 524288, attn_qkv, 786432, nullptr, 0,
                                                big, 786432, 512, 1536, 512, 0);
      rope_kernel<<<4096, 256, 0, stream>>>(big, cosb, sinb, s2t, 1024, 512);
      fattn_kernel<<<dim3(64,8,1), 256, 0, stream>>>(big, ctx, 512);
      gemm128<<<dim3(4,16,4), 256, 0, stream>>>(u + 262144, 524288, ffn_w1, 1048576,
                                                nullptr, 0, big, 1048576,
                                                512, 2048, 512, 1);
      gemm_dual<<<dim3(8,16,4), 256, 0, stream>>>(
          GP{ctx, 262144, attn_o, 262144, xin, 524288, eout, 524288, 512, 512, 512, 0},
          GP{big, 1048576, ffn_w2, 1048576, xin + 262144, 524288, eout + 262144, 524288, 512, 512, 2048, 0},
          8);
    } else {
      // hop 2 (last): outputs only feed the final combine -> bf16 MFMA safe
      gemm_mfma<<<dim3(4,12,4), 256, 0, stream>>>(
          GP{u, 524288, attn_qkv, 786432, nullptr, 0, big, 786432, 512, 1536, 512, 0});
      rope_kernel<<<4096, 256, 0, stream>>>(big, cosb, sinb, s2t, 1024, 512);
      fattn_kernel<<<dim3(64,8,1), 256, 0, stream>>>(big, ctx, 512);
      gemm_mfma<<<dim3(4,16,4), 256, 0, stream>>>(
          GP{u + 262144, 524288, ffn_w1, 1048576, nullptr, 0, big, 1048576, 512, 2048, 512, 1});
      mfma_dual<<<dim3(4,8,4), 256, 0, stream>>>(
          GP{ctx, 262144, attn_o, 262144, xin, 524288, eout, 524288, 512, 512, 512, 0},
          GP{big, 1048576, ffn_w2, 1048576, xin + 262144, 524288, eout + 262144, 524288, 512, 512, 2048, 0},
          4);
    }

    combine_kernel<<<1024, 256, 0, stream>>>(h, eout, t2s, cw);
  }

  final_rmsnorm_kernel<<<2048, 256, 0, stream>>>(h, out, lnout_s);
}

// Round 12
// 1218.488 us; speedup vs baseline: 1.1807x; 1.1807x over previous
//
#include <hip/hip_runtime.h>
#include <hip/hip_bf16.h>

#define T_SEQ 2048
#define DMODEL 512
#define CEXP 512

typedef short s16x4 __attribute__((ext_vector_type(4)));
typedef short s16x8 __attribute__((ext_vector_type(8)));
typedef float f32x4 __attribute__((ext_vector_type(4)));

__device__ __forceinline__ float geluf(float x){
  float x3 = x*x*x;
  return 0.5f*x*(1.f + tanhf(0.7978845608028654f*(x + 0.044715f*x3)));
}

// fp32 -> bf16 (RNE), bit-level
__device__ __forceinline__ unsigned short f2b(float x){
  unsigned int u = __float_as_uint(x);
  u += 0x7fffu + ((u >> 16) & 1u);
  return (unsigned short)(u >> 16);
}

// GEMM params (by value to kernels; strides in elements)
struct GP {
  const float* A; long As;
  const float* W; long Ws;
  const float* R; long Rs;
  float* O; long Os;
  int M, N, K, act;
};

// ---------------- embed (float4) ----------------
__global__ void embed_kernel(const int* __restrict__ ids, const float* __restrict__ ew,
                             float* __restrict__ h){
  int idx = blockIdx.x*256 + threadIdx.x;   // T*128 exact
  int t = idx >> 7, d4 = idx & 127;
  *(float4*)&h[(size_t)idx*4] = *(const float4*)&ew[(size_t)ids[t]*DMODEL + d4*4];
}

// ---------------- rope table ----------------
__global__ void rope_table_kernel(float* __restrict__ cosb, float* __restrict__ sinb){
  int idx = blockIdx.x*256 + threadIdx.x;   // T*64 exact
  int t = idx >> 6, i = idx & 63, j = i & 31;
  float inv = powf(10000.f, -(float)(2*j)/64.f);
  float a = (float)t * inv;
  cosb[idx] = cosf(a);
  sinb[idx] = sinf(a);
}

// ---------------- rmsnorm (grouped rows; per-group scale) ----------------
__global__ void rmsnorm_kernel(const float* __restrict__ in, float* __restrict__ out,
                               const float* __restrict__ scale,
                               int rows_per_group, long gstride, int scale_stride){
  int row = blockIdx.x;
  int g = row / rows_per_group, lr = row - g*rows_per_group;
  const float* x = in  + (size_t)g*gstride + (size_t)lr*DMODEL;
  float*       y = out + (size_t)g*gstride + (size_t)lr*DMODEL;
  const float* s = scale + (size_t)g*scale_stride;
  int tid = threadIdx.x;
  float ss = 0.f;
  for (int i = tid; i < DMODEL; i += 256){ float v = x[i]; ss += v*v; }
  __shared__ float red[256];
  red[tid] = ss; __syncthreads();
  for (int st = 128; st > 0; st >>= 1){ if (tid < st) red[tid] += red[tid+st]; __syncthreads(); }
  float r = rsqrtf(red[0]*(1.f/DMODEL) + 1e-6f);
  for (int i = tid; i < DMODEL; i += 256) y[i] = x[i]*r*s[i];
}

// both hop rmsnorm halves in one launch (block picks half). Per-row math
// identical to rmsnorm_kernel -> bit-identical.
__global__ void rmsnorm_dual_kernel(const float* __restrict__ in1, float* __restrict__ out1,
                                    const float* __restrict__ sc1,
                                    const float* __restrict__ in2, float* __restrict__ out2,
                                    const float* __restrict__ sc2,
                                    int rows_per_group, long gstride, int scale_stride, int nrows){
  int row = blockIdx.x;
  const float* in; float* out; const float* scale;
  if (row < nrows){ in = in1; out = out1; scale = sc1; }
  else            { in = in2; out = out2; scale = sc2; row -= nrows; }
  int g = row / rows_per_group, lr = row - g*rows_per_group;
  const float* x = in  + (size_t)g*gstride + (size_t)lr*DMODEL;
  float*       y = out + (size_t)g*gstride + (size_t)lr*DMODEL;
  const float* s = scale + (size_t)g*scale_stride;
  int tid = threadIdx.x;
  float ss = 0.f;
  for (int i = tid; i < DMODEL; i += 256){ float v = x[i]; ss += v*v; }
  __shared__ float red[256];
  red[tid] = ss; __syncthreads();
  for (int st = 128; st > 0; st >>= 1){ if (tid < st) red[tid] += red[tid+st]; __syncthreads(); }
  float r = rsqrtf(red[0]*(1.f/DMODEL) + 1e-6f);
  for (int i = tid; i < DMODEL; i += 256) y[i] = x[i]*r*s[i];
}

__global__ void final_rmsnorm_kernel(const float* __restrict__ in, float* __restrict__ out,
                                     const float* __restrict__ scale){
  int row = blockIdx.x;
  const float* x = in + (size_t)row*DMODEL;
  int tid = threadIdx.x;
  float ss = 0.f;
  for (int i = tid; i < DMODEL; i += 256){ float v = x[i]; ss += v*v; }
  __shared__ float red[256];
  red[tid] = ss; __syncthreads();
  for (int st = 128; st > 0; st >>= 1){ if (tid < st) red[tid] += red[tid+st]; __syncthreads(); }
  float r = rsqrtf(red[0]*(1.f/DMODEL) + 1e-6f);
  for (int i = tid; i < DMODEL; i += 256)
    out[(size_t)row*DMODEL + i] = x[i]*r*scale[i];
}

// ---------------- fp32 GEMM 64x64 body (register-prefetch, bit-identical order) ----------------
__device__ __forceinline__ void gemm64_body(GP g, int bx, int by, int bz){
  const float* A = g.A + (size_t)bz*g.As;
  const float* W = g.W + (size_t)bz*g.Ws;
  const float* Res = g.R ? g.R + (size_t)bz*g.Rs : nullptr;
  float* Out = g.O + (size_t)bz*g.Os;
  int M = g.M, N = g.N, K = g.K, act = g.act;
  __shared__ float As[16][68];
  __shared__ float Ws[16][68];
  int tid = threadIdx.x;
  int tx = tid & 15, ty = tid >> 4;
  int row0 = bx*64, col0 = by*64;
  float acc[4][4] = {{0.f}};
  int sm = tid >> 2;               // staged row 0..63
  int skq = (tid & 3) << 2;        // staged k-chunk 0,4,8,12
  int gm = row0 + sm, gn = col0 + sm;

  float4 va = make_float4(0.f,0.f,0.f,0.f);
  float4 vw = make_float4(0.f,0.f,0.f,0.f);
  if (gm < M) va = *(const float4*)&A[(size_t)gm*K + skq];
  if (gn < N) vw = *(const float4*)&W[(size_t)gn*K + skq];

  for (int k0 = 0; k0 < K; k0 += 16){
    __syncthreads();
    As[skq+0][sm] = va.x; As[skq+1][sm] = va.y; As[skq+2][sm] = va.z; As[skq+3][sm] = va.w;
    Ws[skq+0][sm] = vw.x; Ws[skq+1][sm] = vw.y; Ws[skq+2][sm] = vw.z; Ws[skq+3][sm] = vw.w;
    __syncthreads();
    if (k0 + 16 < K){
      if (gm < M) va = *(const float4*)&A[(size_t)gm*K + k0 + 16 + skq];
      if (gn < N) vw = *(const float4*)&W[(size_t)gn*K + k0 + 16 + skq];
    }
    #pragma unroll
    for (int kk = 0; kk < 16; ++kk){
      float4 av = *(const float4*)&As[kk][ty*4];
      float4 wv = *(const float4*)&Ws[kk][tx*4];
      float a[4] = {av.x, av.y, av.z, av.w};
      float w[4] = {wv.x, wv.y, wv.z, wv.w};
      #pragma unroll
      for (int i = 0; i < 4; ++i)
        #pragma unroll
        for (int j = 0; j < 4; ++j)
          acc[i][j] += a[i]*w[j];
    }
  }
  #pragma unroll
  for (int i = 0; i < 4; ++i){
    int om = row0 + ty*4 + i;
    if (om >= M) continue;
    #pragma unroll
    for (int j = 0; j < 4; ++j){
      int on = col0 + tx*4 + j;
      if (on >= N) continue;
      float v = acc[i][j];
      if (act == 1) v = geluf(v);
      if (Res) v += Res[(size_t)om*N + on];
      Out[(size_t)om*N + on] = v;
    }
  }
}

__global__ __launch_bounds__(256)
void gemm_kernel(GP g){ gemm64_body(g, blockIdx.x, blockIdx.y, blockIdx.z); }

// dual: y < ysplit -> g1, else g2 (y shifted). Each block computes exactly
// what it did as a standalone launch -> bit-identical.
__global__ __launch_bounds__(256)
void gemm_dual(GP g1, GP g2, int ysplit){
  bool first = (int)blockIdx.y < ysplit;
  GP g = first ? g1 : g2;
  int by = first ? blockIdx.y : blockIdx.y - ysplit;
  gemm64_body(g, blockIdx.x, by, blockIdx.z);
}

// ---------------- fp32 GEMM 128x128, 8x8/thread (N=1536/2048 shapes) ----------------
__global__ __launch_bounds__(256)
void gemm128(const float* __restrict__ A, long Astride,
             const float* __restrict__ W, long Wstride,
             const float* __restrict__ Res, long Rstride,
             float* __restrict__ Out, long Ostride,
             int M, int N, int K, int act){
  int b = blockIdx.z;
  A += (size_t)b*Astride; W += (size_t)b*Wstride; Out += (size_t)b*Ostride;
  if (Res) Res += (size_t)b*Rstride;
  __shared__ float As[16][132];
  __shared__ float Ws[16][132];
  int tid = threadIdx.x;
  int r0 = (tid >> 4) * 8;
  int c0 = (tid & 15) * 8;
  int row0 = blockIdx.x*128, col0 = blockIdx.y*128;
  int sr = tid >> 1;
  int sc = (tid & 1) * 8;
  float acc[8][8] = {{0.f}};

  float4 a0 = *(const float4*)&A[(size_t)(row0+sr)*K + sc];
  float4 a1 = *(const float4*)&A[(size_t)(row0+sr)*K + sc + 4];
  float4 w0 = *(const float4*)&W[(size_t)(col0+sr)*K + sc];
  float4 w1 = *(const float4*)&W[(size_t)(col0+sr)*K + sc + 4];

  for (int k0 = 0; k0 < K; k0 += 16){
    __syncthreads();
    As[sc+0][sr]=a0.x; As[sc+1][sr]=a0.y; As[sc+2][sr]=a0.z; As[sc+3][sr]=a0.w;
    As[sc+4][sr]=a1.x; As[sc+5][sr]=a1.y; As[sc+6][sr]=a1.z; As[sc+7][sr]=a1.w;
    Ws[sc+0][sr]=w0.x; Ws[sc+1][sr]=w0.y; Ws[sc+2][sr]=w0.z; Ws[sc+3][sr]=w0.w;
    Ws[sc+4][sr]=w1.x; Ws[sc+5][sr]=w1.y; Ws[sc+6][sr]=w1.z; Ws[sc+7][sr]=w1.w;
    __syncthreads();
    if (k0 + 16 < K){
      a0 = *(const float4*)&A[(size_t)(row0+sr)*K + k0 + 16 + sc];
      a1 = *(const float4*)&A[(size_t)(row0+sr)*K + k0 + 16 + sc + 4];
      w0 = *(const float4*)&W[(size_t)(col0+sr)*K + k0 + 16 + sc];
      w1 = *(const float4*)&W[(size_t)(col0+sr)*K + k0 + 16 + sc + 4];
    }
    #pragma unroll
    for (int kk = 0; kk < 16; ++kk){
      float a[8], w[8];
      *(float4*)&a[0] = *(const float4*)&As[kk][r0];
      *(float4*)&a[4] = *(const float4*)&As[kk][r0+4];
      *(float4*)&w[0] = *(const float4*)&Ws[kk][c0];
      *(float4*)&w[4] = *(const float4*)&Ws[kk][c0+4];
      #pragma unroll
      for (int i = 0; i < 8; ++i)
        #pragma unroll
        for (int j = 0; j < 8; ++j)
          acc[i][j] += a[i]*w[j];
    }
  }

  #pragma unroll
  for (int i = 0; i < 8; ++i){
    int gm = row0 + r0 + i;
    #pragma unroll
    for (int jj = 0; jj < 2; ++jj){
      int gn = col0 + c0 + jj*4;
      float4 v;
      v.x = acc[i][jj*4+0]; v.y = acc[i][jj*4+1];
      v.z = acc[i][jj*4+2]; v.w = acc[i][jj*4+3];
      if (act == 1){ v.x = geluf(v.x); v.y = geluf(v.y); v.z = geluf(v.z); v.w = geluf(v.w); }
      if (Res){
        float4 rv = *(const float4*)&Res[(size_t)gm*N + gn];
        v.x += rv.x; v.y += rv.y; v.z += rv.z; v.w += rv.w;
      }
      *(float4*)&Out[(size_t)gm*N + gn] = v;
    }
  }
}

// ---------------- MFMA bf16 GEMM body (non-routing: last-hop experts) ----------------
__device__ __forceinline__ void mfma_body(GP g, int bx, int by, int bz){
  const float* A = g.A + (size_t)bz*g.As;
  const float* W = g.W + (size_t)bz*g.Ws;
  const float* Res = g.R ? g.R + (size_t)bz*g.Rs : nullptr;
  float* Out = g.O + (size_t)bz*g.Os;
  int N = g.N, K = g.K, act = g.act;

  __shared__ short As[128][40];   // 80 B row stride: 16B-aligned, <=2-way banks
  __shared__ short Ws[128][40];

  int tid = threadIdx.x;
  int l = tid & 63, w = tid >> 6;
  int wrow = (w >> 1)*64, wcol = (w & 1)*64;
  int row0 = bx*128, col0 = by*128;
  int lm = l & 15, lq = l >> 4;

  f32x4 acc[4][4];
  #pragma unroll
  for (int i = 0; i < 4; ++i)
    #pragma unroll
    for (int j = 0; j < 4; ++j)
      acc[i][j] = (f32x4){0.f,0.f,0.f,0.f};

  for (int k0 = 0; k0 < K; k0 += 32){
    #pragma unroll
    for (int t = 0; t < 4; ++t){
      int f4 = tid + t*256;
      int r = f4 >> 3, kq = f4 & 7;
      float4 va = *(const float4*)&A[(size_t)(row0 + r)*K + k0 + kq*4];
      s16x4 pa; pa[0]=(short)f2b(va.x); pa[1]=(short)f2b(va.y); pa[2]=(short)f2b(va.z); pa[3]=(short)f2b(va.w);
      *(s16x4*)&As[r][kq*4] = pa;
      float4 vw = *(const float4*)&W[(size_t)(col0 + r)*K + k0 + kq*4];
      s16x4 pw; pw[0]=(short)f2b(vw.x); pw[1]=(short)f2b(vw.y); pw[2]=(short)f2b(vw.z); pw[3]=(short)f2b(vw.w);
      *(s16x4*)&Ws[r][kq*4] = pw;
    }
    __syncthreads();

    s16x8 af[4], bf[4];
    #pragma unroll
    for (int rt = 0; rt < 4; ++rt)
      af[rt] = *(s16x8*)&As[wrow + rt*16 + lm][lq*8];
    #pragma unroll
    for (int ct = 0; ct < 4; ++ct)
      bf[ct] = *(s16x8*)&Ws[wcol + ct*16 + lm][lq*8];
    #pragma unroll
    for (int rt = 0; rt < 4; ++rt)
      #pragma unroll
      for (int ct = 0; ct < 4; ++ct)
        acc[rt][ct] = __builtin_amdgcn_mfma_f32_16x16x32_bf16(af[rt], bf[ct], acc[rt][ct], 0, 0, 0);
    __syncthreads();
  }

  #pragma unroll
  for (int rt = 0; rt < 4; ++rt){
    #pragma unroll
    for (int p = 0; p < 4; ++p){
      int row = row0 + wrow + rt*16 + lq*4 + p;
      #pragma unroll
      for (int ct = 0; ct < 4; ++ct){
        int col = col0 + wcol + ct*16 + lm;
        float v = acc[rt][ct][p];
        if (act == 1) v = geluf(v);
        if (Res) v += Res[(size_t)row*N + col];
        Out[(size_t)row*N + col] = v;
      }
    }
  }
}

__global__ __launch_bounds__(256)
void gemm_mfma(GP g){ mfma_body(g, blockIdx.x, blockIdx.y, blockIdx.z); }

__global__ __launch_bounds__(256)
void mfma_dual(GP g1, GP g2, int ysplit){
  bool first = (int)blockIdx.y < ysplit;
  GP g = first ? g1 : g2;
  int by = first ? blockIdx.y : blockIdx.y - ysplit;
  mfma_body(g, blockIdx.x, by, blockIdx.z);
}

// ---------------- RoPE apply in-place on qkv rows ----------------
__global__ void rope_kernel(float* __restrict__ qkv, const float* __restrict__ cosb,
                            const float* __restrict__ sinb, const int* __restrict__ map,
                            int map_gstride, int rows_per_group){
  int idx = blockIdx.x*256 + threadIdx.x;   // rows*512 exact
  int row = idx >> 9;
  int rem = idx & 511;
  int sec = rem >> 8;           // 0=q, 1=k
  int hh  = (rem >> 5) & 7;
  int j   = rem & 31;
  int t;
  if (map){
    t = map[(row/rows_per_group)*map_gstride + (row % rows_per_group)];
    if (t < 0) return;
  } else {
    t = row;
  }
  float c = cosb[t*64 + j], s = sinb[t*64 + j];
  float* p = qkv + (size_t)row*1536 + sec*512 + hh*64;
  float a = p[j], b = p[j+32];
  p[j]    = a*c - b*s;
  p[j+32] = b*c + a*s;
}

// ---------------- flash attention: paired 16q tiles, XCD-swizzled ----------------
// r12: EXACT r10 body restored (223us, verified twice). r11's 2-tile K stage
// made V-prefetch regs conditionally live inside a wrapping loop -> scratch
// (WRITE 6MB->346MB). RULE (3rd incident): fattn registers stay in VGPRs only
// when the per-k-tile body is one straight-line region reached unconditionally.
// Do NOT restructure this loop again. XCD swizzle (r8: FETCH 52.7->7.2MB) +
// heavy+light pairing (r7) retained. Bit-identical, routing-safe.
__global__ __launch_bounds__(256, 3)
void fattn_kernel(const float* __restrict__ qkv, float* __restrict__ ctx, int C){
  int tps = C >> 4;                 // 16-row q tiles per sequence (even)
  int pairs = tps >> 1;
  int lin = blockIdx.y * gridDim.x + blockIdx.x;   // hardware linear id
  int hh  = lin & 7;                // XCD-local head
  int bx  = lin >> 3;
  int seq = bx / pairs;
  int pr  = bx - seq*pairs;
  size_t base = (size_t)seq * C * 1536;
  const float* Qg = qkv + base + hh*64;
  const float* Kg = qkv + base + 512 + hh*64;
  const float* Vg = qkv + base + 1024 + hh*64;

  __shared__ float Qs[16][68];
  __shared__ float Ks[64][68];
  __shared__ float Ps[16][68];

  int tid = threadIdx.x;
  int tx = tid & 15, ty = tid >> 4;   // ty = owned q row (0..15)

  #pragma unroll 1
  for (int half = 0; half < 2; ++half){
    int lt = half ? pr : (tps - 1 - pr);   // heavy tile first
    int q0 = lt << 4;
    if (half) __syncthreads();             // all half-0 LDS reads complete

    // Q stage: exactly one float4 per thread
    *(float4*)&Qs[ty][tx*4] = *(const float4*)&Qg[(size_t)(q0 + ty)*1536 + tx*4];

    float o[4] = {0.f, 0.f, 0.f, 0.f};
    float mrow = -1e30f, lrow = 0.f;

    int nkt = (lt >> 2) + 1;            // k-tiles are 64 wide
    for (int kt = 0; kt < nkt; ++kt){
      int k0 = kt << 6;
      if (kt) __syncthreads();          // previous tile's Ks reads complete
      for (int i = tid; i < 64*16; i += 256){
        int r = i >> 4, dq = i & 15;
        *(float4*)&Ks[r][dq*4] = *(const float4*)&Kg[(size_t)(k0 + r)*1536 + dq*4];
      }
      __syncthreads();

      // issue first V row-group early: latency hides under QK^T
      const float* vbase = Vg + (size_t)k0*1536 + tx*4;
      float4 nv0 = *(const float4*)(vbase + 0*1536);
      float4 nv1 = *(const float4*)(vbase + 1*1536);
      float4 nv2 = *(const float4*)(vbase + 2*1536);
      float4 nv3 = *(const float4*)(vbase + 3*1536);

      float s[4] = {0.f, 0.f, 0.f, 0.f};
      #pragma unroll
      for (int d = 0; d < 64; d += 4){
        float4 qv = *(const float4*)&Qs[ty][d];
        float4 kv[4];
        #pragma unroll
        for (int j = 0; j < 4; ++j) kv[j] = *(const float4*)&Ks[j*16+tx][d];
        #pragma unroll
        for (int j = 0; j < 4; ++j)
          s[j] += qv.x*kv[j].x + qv.y*kv[j].y + qv.z*kv[j].z + qv.w*kv[j].w;
      }
      {
        int q = q0 + ty;
        #pragma unroll
        for (int j = 0; j < 4; ++j){
          int k = k0 + j*16 + tx;
          s[j] = (k <= q) ? s[j]*0.125f : -1e30f;
        }
      }
      {
        float m2 = fmaxf(fmaxf(s[0], s[1]), fmaxf(s[2], s[3]));
        #pragma unroll
        for (int off = 1; off < 16; off <<= 1)
          m2 = fmaxf(m2, __shfl_xor(m2, off, 64));
        float mnew = fmaxf(mrow, m2);
        float alpha = __expf(mrow - mnew);
        float p0 = __expf(s[0] - mnew);
        float p1 = __expf(s[1] - mnew);
        float p2 = __expf(s[2] - mnew);
        float p3 = __expf(s[3] - mnew);
        float rs = (p0 + p1) + (p2 + p3);
        #pragma unroll
        for (int off = 1; off < 16; off <<= 1)
          rs += __shfl_xor(rs, off, 64);
        lrow = lrow*alpha + rs;
        mrow = mnew;
        #pragma unroll
        for (int j = 0; j < 4; ++j) o[j] *= alpha;
        Ps[ty][tx]    = p0;
        Ps[ty][16+tx] = p1;
        Ps[ty][32+tx] = p2;
        Ps[ty][48+tx] = p3;
      }
      {
        #pragma unroll
        for (int kc = 0; kc < 16; ++kc){
          float4 v0 = nv0, v1 = nv1, v2 = nv2, v3 = nv3;
          if (kc < 15){
            const float* nb = vbase + (size_t)(kc+1)*4*1536;
            nv0 = *(const float4*)(nb + 0*1536);
            nv1 = *(const float4*)(nb + 1*1536);
            nv2 = *(const float4*)(nb + 2*1536);
            nv3 = *(const float4*)(nb + 3*1536);
          }
          float4 pr4 = *(const float4*)&Ps[ty][kc*4];
          o[0] += pr4.x*v0.x + pr4.y*v1.x + pr4.z*v2.x + pr4.w*v3.x;
          o[1] += pr4.x*v0.y + pr4.y*v1.y + pr4.z*v2.y + pr4.w*v3.y;
          o[2] += pr4.x*v0.z + pr4.y*v1.z + pr4.z*v2.z + pr4.w*v3.z;
          o[3] += pr4.x*v0.w + pr4.y*v1.w + pr4.z*v2.w + pr4.w*v3.w;
        }
      }
    }

    float inv = 1.f / lrow;
    float4 res;
    res.x = o[0]*inv; res.y = o[1]*inv; res.z = o[2]*inv; res.w = o[3]*inv;
    *(float4*)(ctx + (size_t)(seq*C + q0 + ty)*512 + hh*64 + tx*4) = res;
  }
}

// ---------------- router: softmax over 9, top-2 mask ----------------
__global__ void router_kernel(const float* __restrict__ logits, float* __restrict__ probs,
                              int* __restrict__ maskb){
  int t = blockIdx.x*256 + threadIdx.x;
  if (t >= T_SEQ) return;
  float v[9];
  float mx = -1e30f;
  for (int e = 0; e < 9; ++e){ v[e] = logits[t*9+e]; mx = fmaxf(mx, v[e]); }
  float s = 0.f;
  for (int e = 0; e < 9; ++e) s += expf(v[e]-mx);
  float inv = 1.f/s;
  for (int e = 0; e < 8; ++e) probs[t*8+e] = expf(v[e]-mx)*inv;
  int i1 = 0;
  for (int e = 1; e < 9; ++e) if (v[e] > v[i1]) i1 = e;
  int i2 = -1;
  for (int e = 0; e < 9; ++e){ if (e == i1) continue; if (i2 < 0 || v[e] > v[i2]) i2 = e; }
  maskb[t] = (1<<i1) | (1<<i2);
}

__global__ void seti_kernel(int* __restrict__ p, int v, int n){
  int i = blockIdx.x*256 + threadIdx.x;
  if (i < n) p[i] = v;
}

// ---------------- capacity ranking ----------------
__global__ void rank_kernel(const float* __restrict__ probs, const int* __restrict__ maskb,
                            int* __restrict__ t2s, int* __restrict__ s2t, float* __restrict__ cw){
  int idx = blockIdx.x*256 + threadIdx.x;   // 8*T exact
  int e = idx / T_SEQ, t = idx - e*T_SEQ;
  __shared__ float spm[T_SEQ];
  int tid = threadIdx.x;
  for (int i = tid; i < T_SEQ; i += 256)
    spm[i] = ((maskb[i]>>e)&1) ? probs[i*8+e] : -1.0f;
  __syncthreads();
  int slot = -1; float w = 0.f;
  if ((maskb[t]>>e)&1){
    float p = probs[t*8+e];
    int rank = 0;
    #pragma unroll 8
    for (int t2 = 0; t2 < T_SEQ; ++t2){
      float p2 = spm[t2];
      rank += (p2 > p || (p2 == p && t2 < t)) ? 1 : 0;
    }
    if (rank < CEXP){ slot = rank; w = p; s2t[e*CEXP + rank] = t; }
  }
  t2s[t*8+e] = slot;
  cw[t*8+e] = w;
}

// ---------------- gather (float4) ----------------
__global__ void gather_kernel(const float* __restrict__ h, const int* __restrict__ s2t,
                              float* __restrict__ xin){
  int idx = blockIdx.x*256 + threadIdx.x;   // 8*CEXP*128 exact
  int row = idx >> 7, d4 = idx & 127;
  int t = s2t[row];
  float4 v = make_float4(0.f,0.f,0.f,0.f);
  if (t >= 0) v = *(const float4*)&h[(size_t)t*DMODEL + d4*4];
  *(float4*)&xin[(size_t)idx*4] = v;
}

// ---------------- combine (float4; per-element order unchanged) ----------------
__global__ void combine_kernel(float* __restrict__ h, const float* __restrict__ eout,
                               const int* __restrict__ t2s, const float* __restrict__ cw){
  int idx = blockIdx.x*256 + threadIdx.x;   // T*128 exact
  int t = idx >> 7, d4 = idx & 127;
  float4 acc = make_float4(0.f,0.f,0.f,0.f);
  float rho = 0.f;
  for (int e = 0; e < 8; ++e){
    int c = t2s[t*8+e];
    if (c >= 0){
      float w = cw[t*8+e];
      rho += w;
      float4 ev = *(const float4*)&eout[((size_t)e*CEXP + c)*DMODEL + d4*4];
      acc.x += w*ev.x; acc.y += w*ev.y; acc.z += w*ev.z; acc.w += w*ev.w;
    }
  }
  float4 hv = *(float4*)&h[(size_t)idx*4];
  float4 r;
  r.x = hv.x + acc.x - rho*hv.x;
  r.y = hv.y + acc.y - rho*hv.y;
  r.z = hv.z + acc.z - rho*hv.z;
  r.w = hv.w + acc.w - rho*hv.w;
  *(float4*)&h[(size_t)idx*4] = r;
}

extern "C" void kernel_launch(void* const* d_in, const int* in_sizes, int n_in,
                              void* d_out, int out_size, void* d_ws, size_t ws_size,
                              hipStream_t stream){
  const int*   ids      = (const int*)  d_in[0];
  const float* embed_w  = (const float*)d_in[1];
  const float* router_w = (const float*)d_in[2];
  const float* attn_qkv = (const float*)d_in[3];
  const float* attn_o   = (const float*)d_in[4];
  const float* attn_ln  = (const float*)d_in[5];
  const float* ffn_w1   = (const float*)d_in[6];
  const float* ffn_w2   = (const float*)d_in[7];
  const float* ffn_ln   = (const float*)d_in[8];
  const float* bb_qkv   = (const float*)d_in[9];
  const float* bb_o     = (const float*)d_in[10];
  const float* bb_ln    = (const float*)d_in[11];
  const float* lnout_s  = (const float*)d_in[12];
  float* out = (float*)d_out;

  // ---- workspace layout (floats) ----
  float* W    = (float*)d_ws;
  float* h    = W;                 // 2048*512
  float* cosb = h    + 1048576;    // 2048*64
  float* sinb = cosb + 131072;
  float* xin  = sinb + 131072;     // 8*512*512
  float* u    = xin  + 2097152;
  float* big  = u    + 2097152;    // max(2048*1536, 4*512*2048)
  float* ctx  = big  + 4194304;    // 2048*512
  float* eout = ctx  + 1048576;
  float* logits = eout + 2097152;
  float* probs  = logits + 18432;
  float* cw     = probs  + 16384;
  int* ibase = (int*)(cw + 16384);
  int* maskb = ibase;
  int* t2s   = maskb + 2048;
  int* s2t   = t2s   + 16384;

  embed_kernel<<<1024, 256, 0, stream>>>(ids, embed_w, h);
  rope_table_kernel<<<512, 256, 0, stream>>>(cosb, sinb);

  // ---- backbone attention block (fp32: feeds routing) ----
  rmsnorm_kernel<<<2048, 256, 0, stream>>>(h, u, bb_ln, 2048, 0, 0);
  gemm128<<<dim3(16,12,1), 256, 0, stream>>>(u, 0, bb_qkv, 0, nullptr, 0, big, 0,
                                             2048, 1536, 512, 0);
  rope_kernel<<<4096, 256, 0, stream>>>(big, cosb, sinb, nullptr, 0, 2048);
  fattn_kernel<<<dim3(64,8,1), 256, 0, stream>>>(big, ctx, 2048);
  gemm_kernel<<<dim3(32,8,1), 256, 0, stream>>>(
      GP{ctx, 0, bb_o, 0, h, 0, h, 0, 2048, 512, 512, 0});

  // ---- hops ----
  for (int hop = 0; hop < 2; ++hop){
    const float* wr = router_w + (size_t)hop*9*512;
    gemm_kernel<<<dim3(32,1,1), 256, 0, stream>>>(
        GP{h, 0, wr, 0, nullptr, 0, logits, 0, 2048, 9, 512, 0});
    router_kernel<<<8, 256, 0, stream>>>(logits, probs, maskb);
    seti_kernel<<<16, 256, 0, stream>>>(s2t, -1, 4096);
    rank_kernel<<<64, 256, 0, stream>>>(probs, maskb, t2s, s2t, cw);
    gather_kernel<<<2048, 256, 0, stream>>>(h, s2t, xin);

    rmsnorm_dual_kernel<<<4096, 256, 0, stream>>>(xin,          u,          attn_ln,
                                                  xin + 262144, u + 262144, ffn_ln,
                                                  512, 524288, 512, 2048);

    if (hop == 0){
      // hop 1 feeds hop-2 routing: keep fp32 numerics (round-4 verified).
      gemm128<<<dim3(4,12,4), 256, 0, stream>>>(u, 524288, attn_qkv, 786432, nullptr, 0,
                                                big, 786432, 512, 1536, 512, 0);
      rope_kernel<<<4096, 256, 0, stream>>>(big, cosb, sinb, s2t, 1024, 512);
      fattn_kernel<<<dim3(64,8,1), 256, 0, stream>>>(big, ctx, 512);
      gemm128<<<dim3(4,16,4), 256, 0, stream>>>(u + 262144, 524288, ffn_w1, 1048576,
                                                nullptr, 0, big, 1048576,
                                                512, 2048, 512, 1);
      gemm_dual<<<dim3(8,16,4), 256, 0, stream>>>(
          GP{ctx, 262144, attn_o, 262144, xin, 524288, eout, 524288, 512, 512, 512, 0},
          GP{big, 1048576, ffn_w2, 1048576, xin + 262144, 524288, eout + 262144, 524288, 512, 512, 2048, 0},
          8);
    } else {
      // hop 2 (last): outputs only feed the final combine -> bf16 MFMA safe
      gemm_mfma<<<dim3(4,12,4), 256, 0, stream>>>(
          GP{u, 524288, attn_qkv, 786432, nullptr, 0, big, 786432, 512, 1536, 512, 0});
      rope_kernel<<<4096, 256, 0, stream>>>(big, cosb, sinb, s2t, 1024, 512);
      fattn_kernel<<<dim3(64,8,1), 256, 0, stream>>>(big, ctx, 512);
      gemm_mfma<<<dim3(4,16,4), 256, 0, stream>>>(
          GP{u + 262144, 524288, ffn_w1, 1048576, nullptr, 0, big, 1048576, 512, 2048, 512, 1});
      mfma_dual<<<dim3(4,8,4), 256, 0, stream>>>(
          GP{ctx, 262144, attn_o, 262144, xin, 524288, eout, 524288, 512, 512, 512, 0},
          GP{big, 1048576, ffn_w2, 1048576, xin + 262144, 524288, eout + 262144, 524288, 512, 512, 2048, 0},
          4);
    }

    combine_kernel<<<1024, 256, 0, stream>>>(h, eout, t2s, cw);
  }

  final_rmsnorm_kernel<<<2048, 256, 0, stream>>>(h, out, lnout_s);
}

// Round 13
// 1205.649 us; speedup vs baseline: 1.1933x; 1.0106x over previous
//
#include <hip/hip_runtime.h>
#include <hip/hip_bf16.h>

#define T_SEQ 2048
#define DMODEL 512
#define CEXP 512

typedef short s16x4 __attribute__((ext_vector_type(4)));
typedef short s16x8 __attribute__((ext_vector_type(8)));
typedef float f32x4 __attribute__((ext_vector_type(4)));

__device__ __forceinline__ float geluf(float x){
  float x3 = x*x*x;
  return 0.5f*x*(1.f + tanhf(0.7978845608028654f*(x + 0.044715f*x3)));
}

// fp32 -> bf16 (RNE), bit-level
__device__ __forceinline__ unsigned short f2b(float x){
  unsigned int u = __float_as_uint(x);
  u += 0x7fffu + ((u >> 16) & 1u);
  return (unsigned short)(u >> 16);
}

// GEMM params (by value to kernels; strides in elements)
struct GP {
  const float* A; long As;
  const float* W; long Ws;
  const float* R; long Rs;
  float* O; long Os;
  int M, N, K, act;
};

// ---------------- fused embed + backbone rmsnorm + rope table ----------------
// r13: blocks 0..2047 handle one token row each: write h row (embed) and u row
// (rmsnorm) with the EXACT per-thread load/sum order and LDS reduction tree of
// the former separate kernels -> bit-identical h,u. Blocks 2048..2559 fill the
// rope cos/sin table (identical math). Branch is block-uniform.
__global__ void embed_norm_rope_kernel(const int* __restrict__ ids, const float* __restrict__ ew,
                                       const float* __restrict__ bb_ln,
                                       float* __restrict__ h, float* __restrict__ u,
                                       float* __restrict__ cosb, float* __restrict__ sinb){
  __shared__ float red[256];
  int b = blockIdx.x;
  int tid = threadIdx.x;
  if (b < 2048){
    int t = b;
    const float* src = ew + (size_t)ids[t]*DMODEL;
    float* hr = h + (size_t)t*DMODEL;
    float* ur = u + (size_t)t*DMODEL;
    float v0 = src[tid], v1 = src[tid+256];
    hr[tid] = v0; hr[tid+256] = v1;
    float ss = v0*v0;
    ss += v1*v1;
    red[tid] = ss; __syncthreads();
    for (int st = 128; st > 0; st >>= 1){ if (tid < st) red[tid] += red[tid+st]; __syncthreads(); }
    float r = rsqrtf(red[0]*(1.f/DMODEL) + 1e-6f);
    ur[tid]     = v0*r*bb_ln[tid];
    ur[tid+256] = v1*r*bb_ln[tid+256];
  } else {
    int idx = (b-2048)*256 + tid;   // 512 blocks * 256 = T*64 exact
    int t = idx >> 6, i = idx & 63, j = i & 31;
    float inv = powf(10000.f, -(float)(2*j)/64.f);
    float a = (float)t * inv;
    cosb[idx] = cosf(a);
    sinb[idx] = sinf(a);
  }
}

// both hop rmsnorm halves in one launch (block picks half). Per-row math
// identical to the original rmsnorm -> bit-identical.
__global__ void rmsnorm_dual_kernel(const float* __restrict__ in1, float* __restrict__ out1,
                                    const float* __restrict__ sc1,
                                    const float* __restrict__ in2, float* __restrict__ out2,
                                    const float* __restrict__ sc2,
                                    int rows_per_group, long gstride, int scale_stride, int nrows){
  int row = blockIdx.x;
  const float* in; float* out; const float* scale;
  if (row < nrows){ in = in1; out = out1; scale = sc1; }
  else            { in = in2; out = out2; scale = sc2; row -= nrows; }
  int g = row / rows_per_group, lr = row - g*rows_per_group;
  const float* x = in  + (size_t)g*gstride + (size_t)lr*DMODEL;
  float*       y = out + (size_t)g*gstride + (size_t)lr*DMODEL;
  const float* s = scale + (size_t)g*scale_stride;
  int tid = threadIdx.x;
  float ss = 0.f;
  for (int i = tid; i < DMODEL; i += 256){ float v = x[i]; ss += v*v; }
  __shared__ float red[256];
  red[tid] = ss; __syncthreads();
  for (int st = 128; st > 0; st >>= 1){ if (tid < st) red[tid] += red[tid+st]; __syncthreads(); }
  float r = rsqrtf(red[0]*(1.f/DMODEL) + 1e-6f);
  for (int i = tid; i < DMODEL; i += 256) y[i] = x[i]*r*s[i];
}

// ---------------- fp32 GEMM 64x64 body (register-prefetch, bit-identical order) ----------------
__device__ __forceinline__ void gemm64_body(GP g, int bx, int by, int bz){
  const float* A = g.A + (size_t)bz*g.As;
  const float* W = g.W + (size_t)bz*g.Ws;
  const float* Res = g.R ? g.R + (size_t)bz*g.Rs : nullptr;
  float* Out = g.O + (size_t)bz*g.Os;
  int M = g.M, N = g.N, K = g.K, act = g.act;
  __shared__ float As[16][68];
  __shared__ float Ws[16][68];
  int tid = threadIdx.x;
  int tx = tid & 15, ty = tid >> 4;
  int row0 = bx*64, col0 = by*64;
  float acc[4][4] = {{0.f}};
  int sm = tid >> 2;               // staged row 0..63
  int skq = (tid & 3) << 2;        // staged k-chunk 0,4,8,12
  int gm = row0 + sm, gn = col0 + sm;

  float4 va = make_float4(0.f,0.f,0.f,0.f);
  float4 vw = make_float4(0.f,0.f,0.f,0.f);
  if (gm < M) va = *(const float4*)&A[(size_t)gm*K + skq];
  if (gn < N) vw = *(const float4*)&W[(size_t)gn*K + skq];

  for (int k0 = 0; k0 < K; k0 += 16){
    __syncthreads();
    As[skq+0][sm] = va.x; As[skq+1][sm] = va.y; As[skq+2][sm] = va.z; As[skq+3][sm] = va.w;
    Ws[skq+0][sm] = vw.x; Ws[skq+1][sm] = vw.y; Ws[skq+2][sm] = vw.z; Ws[skq+3][sm] = vw.w;
    __syncthreads();
    if (k0 + 16 < K){
      if (gm < M) va = *(const float4*)&A[(size_t)gm*K + k0 + 16 + skq];
      if (gn < N) vw = *(const float4*)&W[(size_t)gn*K + k0 + 16 + skq];
    }
    #pragma unroll
    for (int kk = 0; kk < 16; ++kk){
      float4 av = *(const float4*)&As[kk][ty*4];
      float4 wv = *(const float4*)&Ws[kk][tx*4];
      float a[4] = {av.x, av.y, av.z, av.w};
      float w[4] = {wv.x, wv.y, wv.z, wv.w};
      #pragma unroll
      for (int i = 0; i < 4; ++i)
        #pragma unroll
        for (int j = 0; j < 4; ++j)
          acc[i][j] += a[i]*w[j];
    }
  }
  #pragma unroll
  for (int i = 0; i < 4; ++i){
    int om = row0 + ty*4 + i;
    if (om >= M) continue;
    #pragma unroll
    for (int j = 0; j < 4; ++j){
      int on = col0 + tx*4 + j;
      if (on >= N) continue;
      float v = acc[i][j];
      if (act == 1) v = geluf(v);
      if (Res) v += Res[(size_t)om*N + on];
      Out[(size_t)om*N + on] = v;
    }
  }
}

__global__ __launch_bounds__(256)
void gemm_kernel(GP g){ gemm64_body(g, blockIdx.x, blockIdx.y, blockIdx.z); }

// dual: y < ysplit -> g1, else g2 (y shifted). Each block computes exactly
// what it did as a standalone launch -> bit-identical.
__global__ __launch_bounds__(256)
void gemm_dual(GP g1, GP g2, int ysplit){
  bool first = (int)blockIdx.y < ysplit;
  GP g = first ? g1 : g2;
  int by = first ? blockIdx.y : blockIdx.y - ysplit;
  gemm64_body(g, blockIdx.x, by, blockIdx.z);
}

// ---------------- fp32 GEMM 128x128, 8x8/thread (N=1536/2048 shapes) ----------------
__global__ __launch_bounds__(256)
void gemm128(const float* __restrict__ A, long Astride,
             const float* __restrict__ W, long Wstride,
             const float* __restrict__ Res, long Rstride,
             float* __restrict__ Out, long Ostride,
             int M, int N, int K, int act){
  int b = blockIdx.z;
  A += (size_t)b*Astride; W += (size_t)b*Wstride; Out += (size_t)b*Ostride;
  if (Res) Res += (size_t)b*Rstride;
  __shared__ float As[16][132];
  __shared__ float Ws[16][132];
  int tid = threadIdx.x;
  int r0 = (tid >> 4) * 8;
  int c0 = (tid & 15) * 8;
  int row0 = blockIdx.x*128, col0 = blockIdx.y*128;
  int sr = tid >> 1;
  int sc = (tid & 1) * 8;
  float acc[8][8] = {{0.f}};

  float4 a0 = *(const float4*)&A[(size_t)(row0+sr)*K + sc];
  float4 a1 = *(const float4*)&A[(size_t)(row0+sr)*K + sc + 4];
  float4 w0 = *(const float4*)&W[(size_t)(col0+sr)*K + sc];
  float4 w1 = *(const float4*)&W[(size_t)(col0+sr)*K + sc + 4];

  for (int k0 = 0; k0 < K; k0 += 16){
    __syncthreads();
    As[sc+0][sr]=a0.x; As[sc+1][sr]=a0.y; As[sc+2][sr]=a0.z; As[sc+3][sr]=a0.w;
    As[sc+4][sr]=a1.x; As[sc+5][sr]=a1.y; As[sc+6][sr]=a1.z; As[sc+7][sr]=a1.w;
    Ws[sc+0][sr]=w0.x; Ws[sc+1][sr]=w0.y; Ws[sc+2][sr]=w0.z; Ws[sc+3][sr]=w0.w;
    Ws[sc+4][sr]=w1.x; Ws[sc+5][sr]=w1.y; Ws[sc+6][sr]=w1.z; Ws[sc+7][sr]=w1.w;
    __syncthreads();
    if (k0 + 16 < K){
      a0 = *(const float4*)&A[(size_t)(row0+sr)*K + k0 + 16 + sc];
      a1 = *(const float4*)&A[(size_t)(row0+sr)*K + k0 + 16 + sc + 4];
      w0 = *(const float4*)&W[(size_t)(col0+sr)*K + k0 + 16 + sc];
      w1 = *(const float4*)&W[(size_t)(col0+sr)*K + k0 + 16 + sc + 4];
    }
    #pragma unroll
    for (int kk = 0; kk < 16; ++kk){
      float a[8], w[8];
      *(float4*)&a[0] = *(const float4*)&As[kk][r0];
      *(float4*)&a[4] = *(const float4*)&As[kk][r0+4];
      *(float4*)&w[0] = *(const float4*)&Ws[kk][c0];
      *(float4*)&w[4] = *(const float4*)&Ws[kk][c0+4];
      #pragma unroll
      for (int i = 0; i < 8; ++i)
        #pragma unroll
        for (int j = 0; j < 8; ++j)
          acc[i][j] += a[i]*w[j];
    }
  }

  #pragma unroll
  for (int i = 0; i < 8; ++i){
    int gm = row0 + r0 + i;
    #pragma unroll
    for (int jj = 0; jj < 2; ++jj){
      int gn = col0 + c0 + jj*4;
      float4 v;
      v.x = acc[i][jj*4+0]; v.y = acc[i][jj*4+1];
      v.z = acc[i][jj*4+2]; v.w = acc[i][jj*4+3];
      if (act == 1){ v.x = geluf(v.x); v.y = geluf(v.y); v.z = geluf(v.z); v.w = geluf(v.w); }
      if (Res){
        float4 rv = *(const float4*)&Res[(size_t)gm*N + gn];
        v.x += rv.x; v.y += rv.y; v.z += rv.z; v.w += rv.w;
      }
      *(float4*)&Out[(size_t)gm*N + gn] = v;
    }
  }
}

// ---------------- MFMA bf16 GEMM body (non-routing: last-hop experts) ----------------
__device__ __forceinline__ void mfma_body(GP g, int bx, int by, int bz){
  const float* A = g.A + (size_t)bz*g.As;
  const float* W = g.W + (size_t)bz*g.Ws;
  const float* Res = g.R ? g.R + (size_t)bz*g.Rs : nullptr;
  float* Out = g.O + (size_t)bz*g.Os;
  int N = g.N, K = g.K, act = g.act;

  __shared__ short As[128][40];   // 80 B row stride: 16B-aligned, <=2-way banks
  __shared__ short Ws[128][40];

  int tid = threadIdx.x;
  int l = tid & 63, w = tid >> 6;
  int wrow = (w >> 1)*64, wcol = (w & 1)*64;
  int row0 = bx*128, col0 = by*128;
  int lm = l & 15, lq = l >> 4;

  f32x4 acc[4][4];
  #pragma unroll
  for (int i = 0; i < 4; ++i)
    #pragma unroll
    for (int j = 0; j < 4; ++j)
      acc[i][j] = (f32x4){0.f,0.f,0.f,0.f};

  for (int k0 = 0; k0 < K; k0 += 32){
    #pragma unroll
    for (int t = 0; t < 4; ++t){
      int f4 = tid + t*256;
      int r = f4 >> 3, kq = f4 & 7;
      float4 va = *(const float4*)&A[(size_t)(row0 + r)*K + k0 + kq*4];
      s16x4 pa; pa[0]=(short)f2b(va.x); pa[1]=(short)f2b(va.y); pa[2]=(short)f2b(va.z); pa[3]=(short)f2b(va.w);
      *(s16x4*)&As[r][kq*4] = pa;
      float4 vw = *(const float4*)&W[(size_t)(col0 + r)*K + k0 + kq*4];
      s16x4 pw; pw[0]=(short)f2b(vw.x); pw[1]=(short)f2b(vw.y); pw[2]=(short)f2b(vw.z); pw[3]=(short)f2b(vw.w);
      *(s16x4*)&Ws[r][kq*4] = pw;
    }
    __syncthreads();

    s16x8 af[4], bf[4];
    #pragma unroll
    for (int rt = 0; rt < 4; ++rt)
      af[rt] = *(s16x8*)&As[wrow + rt*16 + lm][lq*8];
    #pragma unroll
    for (int ct = 0; ct < 4; ++ct)
      bf[ct] = *(s16x8*)&Ws[wcol + ct*16 + lm][lq*8];
    #pragma unroll
    for (int rt = 0; rt < 4; ++rt)
      #pragma unroll
      for (int ct = 0; ct < 4; ++ct)
        acc[rt][ct] = __builtin_amdgcn_mfma_f32_16x16x32_bf16(af[rt], bf[ct], acc[rt][ct], 0, 0, 0);
    __syncthreads();
  }

  #pragma unroll
  for (int rt = 0; rt < 4; ++rt){
    #pragma unroll
    for (int p = 0; p < 4; ++p){
      int row = row0 + wrow + rt*16 + lq*4 + p;
      #pragma unroll
      for (int ct = 0; ct < 4; ++ct){
        int col = col0 + wcol + ct*16 + lm;
        float v = acc[rt][ct][p];
        if (act == 1) v = geluf(v);
        if (Res) v += Res[(size_t)row*N + col];
        Out[(size_t)row*N + col] = v;
      }
    }
  }
}

__global__ __launch_bounds__(256)
void gemm_mfma(GP g){ mfma_body(g, blockIdx.x, blockIdx.y, blockIdx.z); }

__global__ __launch_bounds__(256)
void mfma_dual(GP g1, GP g2, int ysplit){
  bool first = (int)blockIdx.y < ysplit;
  GP g = first ? g1 : g2;
  int by = first ? blockIdx.y : blockIdx.y - ysplit;
  mfma_body(g, blockIdx.x, by, blockIdx.z);
}

// ---------------- RoPE apply in-place on qkv rows ----------------
__global__ void rope_kernel(float* __restrict__ qkv, const float* __restrict__ cosb,
                            const float* __restrict__ sinb, const int* __restrict__ map,
                            int map_gstride, int rows_per_group){
  int idx = blockIdx.x*256 + threadIdx.x;   // rows*512 exact
  int row = idx >> 9;
  int rem = idx & 511;
  int sec = rem >> 8;           // 0=q, 1=k
  int hh  = (rem >> 5) & 7;
  int j   = rem & 31;
  int t;
  if (map){
    t = map[(row/rows_per_group)*map_gstride + (row % rows_per_group)];
    if (t < 0) return;
  } else {
    t = row;
  }
  float c = cosb[t*64 + j], s = sinb[t*64 + j];
  float* p = qkv + (size_t)row*1536 + sec*512 + hh*64;
  float a = p[j], b = p[j+32];
  p[j]    = a*c - b*s;
  p[j+32] = b*c + a*s;
}

// ---------------- flash attention: paired 16q tiles, XCD-swizzled ----------------
// r10 body (223us, verified 3x). RULE (r9/r11 incidents): fattn registers stay
// in VGPRs only when the per-k-tile body is one straight-line region reached
// unconditionally. Do NOT restructure this loop. XCD swizzle (r8) + heavy+light
// pairing (r7). Bit-identical, routing-safe.
__global__ __launch_bounds__(256, 3)
void fattn_kernel(const float* __restrict__ qkv, float* __restrict__ ctx, int C){
  int tps = C >> 4;                 // 16-row q tiles per sequence (even)
  int pairs = tps >> 1;
  int lin = blockIdx.y * gridDim.x + blockIdx.x;   // hardware linear id
  int hh  = lin & 7;                // XCD-local head
  int bx  = lin >> 3;
  int seq = bx / pairs;
  int pr  = bx - seq*pairs;
  size_t base = (size_t)seq * C * 1536;
  const float* Qg = qkv + base + hh*64;
  const float* Kg = qkv + base + 512 + hh*64;
  const float* Vg = qkv + base + 1024 + hh*64;

  __shared__ float Qs[16][68];
  __shared__ float Ks[64][68];
  __shared__ float Ps[16][68];

  int tid = threadIdx.x;
  int tx = tid & 15, ty = tid >> 4;   // ty = owned q row (0..15)

  #pragma unroll 1
  for (int half = 0; half < 2; ++half){
    int lt = half ? pr : (tps - 1 - pr);   // heavy tile first
    int q0 = lt << 4;
    if (half) __syncthreads();             // all half-0 LDS reads complete

    // Q stage: exactly one float4 per thread
    *(float4*)&Qs[ty][tx*4] = *(const float4*)&Qg[(size_t)(q0 + ty)*1536 + tx*4];

    float o[4] = {0.f, 0.f, 0.f, 0.f};
    float mrow = -1e30f, lrow = 0.f;

    int nkt = (lt >> 2) + 1;            // k-tiles are 64 wide
    for (int kt = 0; kt < nkt; ++kt){
      int k0 = kt << 6;
      if (kt) __syncthreads();          // previous tile's Ks reads complete
      for (int i = tid; i < 64*16; i += 256){
        int r = i >> 4, dq = i & 15;
        *(float4*)&Ks[r][dq*4] = *(const float4*)&Kg[(size_t)(k0 + r)*1536 + dq*4];
      }
      __syncthreads();

      // issue first V row-group early: latency hides under QK^T
      const float* vbase = Vg + (size_t)k0*1536 + tx*4;
      float4 nv0 = *(const float4*)(vbase + 0*1536);
      float4 nv1 = *(const float4*)(vbase + 1*1536);
      float4 nv2 = *(const float4*)(vbase + 2*1536);
      float4 nv3 = *(const float4*)(vbase + 3*1536);

      float s[4] = {0.f, 0.f, 0.f, 0.f};
      #pragma unroll
      for (int d = 0; d < 64; d += 4){
        float4 qv = *(const float4*)&Qs[ty][d];
        float4 kv[4];
        #pragma unroll
        for (int j = 0; j < 4; ++j) kv[j] = *(const float4*)&Ks[j*16+tx][d];
        #pragma unroll
        for (int j = 0; j < 4; ++j)
          s[j] += qv.x*kv[j].x + qv.y*kv[j].y + qv.z*kv[j].z + qv.w*kv[j].w;
      }
      {
        int q = q0 + ty;
        #pragma unroll
        for (int j = 0; j < 4; ++j){
          int k = k0 + j*16 + tx;
          s[j] = (k <= q) ? s[j]*0.125f : -1e30f;
        }
      }
      {
        float m2 = fmaxf(fmaxf(s[0], s[1]), fmaxf(s[2], s[3]));
        #pragma unroll
        for (int off = 1; off < 16; off <<= 1)
          m2 = fmaxf(m2, __shfl_xor(m2, off, 64));
        float mnew = fmaxf(mrow, m2);
        float alpha = __expf(mrow - mnew);
        float p0 = __expf(s[0] - mnew);
        float p1 = __expf(s[1] - mnew);
        float p2 = __expf(s[2] - mnew);
        float p3 = __expf(s[3] - mnew);
        float rs = (p0 + p1) + (p2 + p3);
        #pragma unroll
        for (int off = 1; off < 16; off <<= 1)
          rs += __shfl_xor(rs, off, 64);
        lrow = lrow*alpha + rs;
        mrow = mnew;
        #pragma unroll
        for (int j = 0; j < 4; ++j) o[j] *= alpha;
        Ps[ty][tx]    = p0;
        Ps[ty][16+tx] = p1;
        Ps[ty][32+tx] = p2;
        Ps[ty][48+tx] = p3;
      }
      {
        #pragma unroll
        for (int kc = 0; kc < 16; ++kc){
          float4 v0 = nv0, v1 = nv1, v2 = nv2, v3 = nv3;
          if (kc < 15){
            const float* nb = vbase + (size_t)(kc+1)*4*1536;
            nv0 = *(const float4*)(nb + 0*1536);
            nv1 = *(const float4*)(nb + 1*1536);
            nv2 = *(const float4*)(nb + 2*1536);
            nv3 = *(const float4*)(nb + 3*1536);
          }
          float4 pr4 = *(const float4*)&Ps[ty][kc*4];
          o[0] += pr4.x*v0.x + pr4.y*v1.x + pr4.z*v2.x + pr4.w*v3.x;
          o[1] += pr4.x*v0.y + pr4.y*v1.y + pr4.z*v2.y + pr4.w*v3.y;
          o[2] += pr4.x*v0.z + pr4.y*v1.z + pr4.z*v2.z + pr4.w*v3.z;
          o[3] += pr4.x*v0.w + pr4.y*v1.w + pr4.z*v2.w + pr4.w*v3.w;
        }
      }
    }

    float inv = 1.f / lrow;
    float4 res;
    res.x = o[0]*inv; res.y = o[1]*inv; res.z = o[2]*inv; res.w = o[3]*inv;
    *(float4*)(ctx + (size_t)(seq*C + q0 + ty)*512 + hh*64 + tx*4) = res;
  }
}

// ---------------- router: softmax over 9, top-2 mask (+ s2t init folded in) ----------------
__global__ void router_kernel(const float* __restrict__ logits, float* __restrict__ probs,
                              int* __restrict__ maskb, int* __restrict__ s2t){
  int t = blockIdx.x*256 + threadIdx.x;
  if (t >= T_SEQ) return;
  s2t[t*2]   = -1;              // 2048 threads x 2 = 4096 slots; rank runs after
  s2t[t*2+1] = -1;
  float v[9];
  float mx = -1e30f;
  for (int e = 0; e < 9; ++e){ v[e] = logits[t*9+e]; mx = fmaxf(mx, v[e]); }
  float s = 0.f;
  for (int e = 0; e < 9; ++e) s += expf(v[e]-mx);
  float inv = 1.f/s;
  for (int e = 0; e < 8; ++e) probs[t*8+e] = expf(v[e]-mx)*inv;
  int i1 = 0;
  for (int e = 1; e < 9; ++e) if (v[e] > v[i1]) i1 = e;
  int i2 = -1;
  for (int e = 0; e < 9; ++e){ if (e == i1) continue; if (i2 < 0 || v[e] > v[i2]) i2 = e; }
  maskb[t] = (1<<i1) | (1<<i2);
}

// ---------------- capacity ranking ----------------
__global__ void rank_kernel(const float* __restrict__ probs, const int* __restrict__ maskb,
                            int* __restrict__ t2s, int* __restrict__ s2t, float* __restrict__ cw){
  int idx = blockIdx.x*256 + threadIdx.x;   // 8*T exact
  int e = idx / T_SEQ, t = idx - e*T_SEQ;
  __shared__ float spm[T_SEQ];
  int tid = threadIdx.x;
  for (int i = tid; i < T_SEQ; i += 256)
    spm[i] = ((maskb[i]>>e)&1) ? probs[i*8+e] : -1.0f;
  __syncthreads();
  int slot = -1; float w = 0.f;
  if ((maskb[t]>>e)&1){
    float p = probs[t*8+e];
    int rank = 0;
    #pragma unroll 8
    for (int t2 = 0; t2 < T_SEQ; ++t2){
      float p2 = spm[t2];
      rank += (p2 > p || (p2 == p && t2 < t)) ? 1 : 0;
    }
    if (rank < CEXP){ slot = rank; w = p; s2t[e*CEXP + rank] = t; }
  }
  t2s[t*8+e] = slot;
  cw[t*8+e] = w;
}

// ---------------- gather (float4) ----------------
__global__ void gather_kernel(const float* __restrict__ h, const int* __restrict__ s2t,
                              float* __restrict__ xin){
  int idx = blockIdx.x*256 + threadIdx.x;   // 8*CEXP*128 exact
  int row = idx >> 7, d4 = idx & 127;
  int t = s2t[row];
  float4 v = make_float4(0.f,0.f,0.f,0.f);
  if (t >= 0) v = *(const float4*)&h[(size_t)t*DMODEL + d4*4];
  *(float4*)&xin[(size_t)idx*4] = v;
}

// ---------------- combine (float4; per-element order unchanged) ----------------
__global__ void combine_kernel(float* __restrict__ h, const float* __restrict__ eout,
                               const int* __restrict__ t2s, const float* __restrict__ cw){
  int idx = blockIdx.x*256 + threadIdx.x;   // T*128 exact
  int t = idx >> 7, d4 = idx & 127;
  float4 acc = make_float4(0.f,0.f,0.f,0.f);
  float rho = 0.f;
  for (int e = 0; e < 8; ++e){
    int c = t2s[t*8+e];
    if (c >= 0){
      float w = cw[t*8+e];
      rho += w;
      float4 ev = *(const float4*)&eout[((size_t)e*CEXP + c)*DMODEL + d4*4];
      acc.x += w*ev.x; acc.y += w*ev.y; acc.z += w*ev.z; acc.w += w*ev.w;
    }
  }
  float4 hv = *(float4*)&h[(size_t)idx*4];
  float4 r;
  r.x = hv.x + acc.x - rho*hv.x;
  r.y = hv.y + acc.y - rho*hv.y;
  r.z = hv.z + acc.z - rho*hv.z;
  r.w = hv.w + acc.w - rho*hv.w;
  *(float4*)&h[(size_t)idx*4] = r;
}

// ---------------- fused last-hop combine + final rmsnorm ----------------
// r13: block handles 2 full rows (threads 0..127 row 2b, 128..255 row 2b+1).
// Combine math identical per element; rmsnorm reduction order differs from the
// old 256-thread kernel but this is the OUTPUT-ONLY path (tolerance-safe,
// routing untouched). h is never written -> saves 8MB traffic + 1 launch.
__global__ void combine_final_kernel(const float* __restrict__ h, const float* __restrict__ eout,
                                     const int* __restrict__ t2s, const float* __restrict__ cw,
                                     const float* __restrict__ scale, float* __restrict__ out){
  int tid = threadIdx.x;
  int row = blockIdx.x*2 + (tid >> 7);
  int d4 = tid & 127;
  float4 acc = make_float4(0.f,0.f,0.f,0.f);
  float rho = 0.f;
  for (int e = 0; e < 8; ++e){
    int c = t2s[row*8+e];
    if (c >= 0){
      float w = cw[row*8+e];
      rho += w;
      float4 ev = *(const float4*)&eout[((size_t)e*CEXP + c)*DMODEL + d4*4];
      acc.x += w*ev.x; acc.y += w*ev.y; acc.z += w*ev.z; acc.w += w*ev.w;
    }
  }
  float4 hv = *(const float4*)&h[(size_t)row*DMODEL + d4*4];
  float4 nh;
  nh.x = hv.x + acc.x - rho*hv.x;
  nh.y = hv.y + acc.y - rho*hv.y;
  nh.z = hv.z + acc.z - rho*hv.z;
  nh.w = hv.w + acc.w - rho*hv.w;
  float ss = nh.x*nh.x + nh.y*nh.y + nh.z*nh.z + nh.w*nh.w;
  __shared__ float red[256];
  red[tid] = ss; __syncthreads();
  for (int st = 64; st > 0; st >>= 1){
    if ((tid & 127) < st) red[tid] += red[tid + st];
    __syncthreads();
  }
  float r = rsqrtf(red[tid & 128]*(1.f/DMODEL) + 1e-6f);
  float4 sc = *(const float4*)&scale[d4*4];
  float4 res;
  res.x = nh.x*r*sc.x; res.y = nh.y*r*sc.y; res.z = nh.z*r*sc.z; res.w = nh.w*r*sc.w;
  *(float4*)&out[(size_t)row*DMODEL + d4*4] = res;
}

extern "C" void kernel_launch(void* const* d_in, const int* in_sizes, int n_in,
                              void* d_out, int out_size, void* d_ws, size_t ws_size,
                              hipStream_t stream){
  const int*   ids      = (const int*)  d_in[0];
  const float* embed_w  = (const float*)d_in[1];
  const float* router_w = (const float*)d_in[2];
  const float* attn_qkv = (const float*)d_in[3];
  const float* attn_o   = (const float*)d_in[4];
  const float* attn_ln  = (const float*)d_in[5];
  const float* ffn_w1   = (const float*)d_in[6];
  const float* ffn_w2   = (const float*)d_in[7];
  const float* ffn_ln   = (const float*)d_in[8];
  const float* bb_qkv   = (const float*)d_in[9];
  const float* bb_o     = (const float*)d_in[10];
  const float* bb_ln    = (const float*)d_in[11];
  const float* lnout_s  = (const float*)d_in[12];
  float* out = (float*)d_out;

  // ---- workspace layout (floats) ----
  float* W    = (float*)d_ws;
  float* h    = W;                 // 2048*512
  float* cosb = h    + 1048576;    // 2048*64
  float* sinb = cosb + 131072;
  float* xin  = sinb + 131072;     // 8*512*512
  float* u    = xin  + 2097152;
  float* big  = u    + 2097152;    // max(2048*1536, 4*512*2048)
  float* ctx  = big  + 4194304;    // 2048*512
  float* eout = ctx  + 1048576;
  float* logits = eout + 2097152;
  float* probs  = logits + 18432;
  float* cw     = probs  + 16384;
  int* ibase = (int*)(cw + 16384);
  int* maskb = ibase;
  int* t2s   = maskb + 2048;
  int* s2t   = t2s   + 16384;

  // ---- fused embed + backbone rmsnorm + rope table ----
  embed_norm_rope_kernel<<<2560, 256, 0, stream>>>(ids, embed_w, bb_ln, h, u, cosb, sinb);

  // ---- backbone attention block (fp32: feeds routing) ----
  gemm128<<<dim3(16,12,1), 256, 0, stream>>>(u, 0, bb_qkv, 0, nullptr, 0, big, 0,
                                             2048, 1536, 512, 0);
  rope_kernel<<<4096, 256, 0, stream>>>(big, cosb, sinb, nullptr, 0, 2048);
  fattn_kernel<<<dim3(64,8,1), 256, 0, stream>>>(big, ctx, 2048);
  gemm_kernel<<<dim3(32,8,1), 256, 0, stream>>>(
      GP{ctx, 0, bb_o, 0, h, 0, h, 0, 2048, 512, 512, 0});

  // ---- hops ----
  for (int hop = 0; hop < 2; ++hop){
    const float* wr = router_w + (size_t)hop*9*512;
    gemm_kernel<<<dim3(32,1,1), 256, 0, stream>>>(
        GP{h, 0, wr, 0, nullptr, 0, logits, 0, 2048, 9, 512, 0});
    router_kernel<<<8, 256, 0, stream>>>(logits, probs, maskb, s2t);
    rank_kernel<<<64, 256, 0, stream>>>(probs, maskb, t2s, s2t, cw);
    gather_kernel<<<2048, 256, 0, stream>>>(h, s2t, xin);

    rmsnorm_dual_kernel<<<4096, 256, 0, stream>>>(xin,          u,          attn_ln,
                                                  xin + 262144, u + 262144, ffn_ln,
                                                  512, 524288, 512, 2048);

    if (hop == 0){
      // hop 1 feeds hop-2 routing: keep fp32 numerics (round-4 verified).
      gemm128<<<dim3(4,12,4), 256, 0, stream>>>(u, 524288, attn_qkv, 786432, nullptr, 0,
                                                big, 786432, 512, 1536, 512, 0);
      rope_kernel<<<4096, 256, 0, stream>>>(big, cosb, sinb, s2t, 1024, 512);
      fattn_kernel<<<dim3(64,8,1), 256, 0, stream>>>(big, ctx, 512);
      gemm128<<<dim3(4,16,4), 256, 0, stream>>>(u + 262144, 524288, ffn_w1, 1048576,
                                                nullptr, 0, big, 1048576,
                                                512, 2048, 512, 1);
      gemm_dual<<<dim3(8,16,4), 256, 0, stream>>>(
          GP{ctx, 262144, attn_o, 262144, xin, 524288, eout, 524288, 512, 512, 512, 0},
          GP{big, 1048576, ffn_w2, 1048576, xin + 262144, 524288, eout + 262144, 524288, 512, 512, 2048, 0},
          8);
      combine_kernel<<<1024, 256, 0, stream>>>(h, eout, t2s, cw);
    } else {
      // hop 2 (last): outputs only feed the final combine -> bf16 MFMA safe
      gemm_mfma<<<dim3(4,12,4), 256, 0, stream>>>(
          GP{u, 524288, attn_qkv, 786432, nullptr, 0, big, 786432, 512, 1536, 512, 0});
      rope_kernel<<<4096, 256, 0, stream>>>(big, cosb, sinb, s2t, 1024, 512);
      fattn_kernel<<<dim3(64,8,1), 256, 0, stream>>>(big, ctx, 512);
      gemm_mfma<<<dim3(4,16,4), 256, 0, stream>>>(
          GP{u + 262144, 524288, ffn_w1, 1048576, nullptr, 0, big, 1048576, 512, 2048, 512, 1});
      mfma_dual<<<dim3(4,8,4), 256, 0, stream>>>(
          GP{ctx, 262144, attn_o, 262144, xin, 524288, eout, 524288, 512, 512, 512, 0},
          GP{big, 1048576, ffn_w2, 1048576, xin + 262144, 524288, eout + 262144, 524288, 512, 512, 2048, 0},
          4);
      // fused combine + final rmsnorm: writes `out` directly, h never touched
      combine_final_kernel<<<1024, 256, 0, stream>>>(h, eout, t2s, cw, lnout_s, out);
    }
  }
}